// Round 4
// baseline (1419.887 us; speedup 1.0000x reference)
//
#include <hip/hip_runtime.h>
#include <cstdint>
#include <cstddef>

// SimpleGCN: h = x@W1+b1; 3x GCNConv(sym-norm adj w/ self loops); sigmoid(h@W2+b2)
// N=100000, d=128, E=1.6M.
// R16 = R15 mega-kernel, but NORMAL launch + hand-rolled grid barrier.
//   R15 post-mortem: absmax 0.5547 == max|ref| vs zeroed output -> the
//   cooperative launch was rejected under the harness's stream capture and the
//   error was swallowed; the kernel never ran. Phase bodies (== R14, passing)
//   are untested-not-falsified. Fix: persistent grid of 1024 blocks
//   (launch_bounds(256,4): VGPR<=128, LDS 5KB -> exactly 4 blocks/CU x 256 CU
//   co-resident, 16 waves/CU) + monotonic-counter barrier:
//   syncthreads; t0{fence(agent) -> atomicAdd(agent) -> RELAXED spin ->
//   fence(agent)}; syncthreads.  Counter zeroed by hipMemsetAsync (capture-ok).
//   Phases: ph0 bucketCount||prep; ph1 colScan||gemmC0; ph2 bucketScatter;
//   ph3 nodeCount; ph4 finalize; ph5 agg0; ph6 gemm1; ph7 agg1+proj; ph8 final.
// R14: LDS two-level counting sort, zero global atomics (R13: returning u64
//   atomics execute memory-side regardless of scope; 22G/s floor).
// Algebra (R11): Wc0 = W1@Wg0, wc2 = Wg2@W2, c2 = bg2.W2+b2.
// rec[] aliases hbuf[] (rec dead before agg0 writes hbuf).

typedef __attribute__((ext_vector_type(8))) short bf16x8;
typedef __attribute__((ext_vector_type(4))) float f32x4;

// ---------- bf16 helpers (packed dword: low 16 bits = element 0) ----------
__device__ __forceinline__ unsigned f2bf(float f) {      // RNE float->bf16 bits
    unsigned u = __float_as_uint(f);
    u += 0x7fffu + ((u >> 16) & 1u);
    return u >> 16;
}
__device__ __forceinline__ float bf_lo(unsigned p) { return __uint_as_float(p << 16); }
__device__ __forceinline__ float bf_hi(unsigned p) { return __uint_as_float(p & 0xffff0000u); }

struct MegaArgs {
    const float* x; const int* row; const int* col; const float* ew;
    const float* W1; const float* b1; const float* Wg; const float* bg;
    const float* W2; const float* b2;
    unsigned short* Wt0; unsigned short* Wt1;
    float* bc0; float* wc2; float* c2;
    unsigned short* tbuf; float* hbuf; unsigned long long* rec;
    unsigned* cnt1; unsigned* total; unsigned* padTotal; unsigned* cntg;
    float* dinv; int* row_ptr; unsigned* edata; float* sbuf; float* out;
    unsigned* gbar;
    int N, E, NB, NC, nGemm, G;
};

// ---------- grid barrier: monotonic counter, all 1024 blocks co-resident ----------
// Release: agent fence (L2 writeback on gfx950) before arrive; acquire: agent
// fence (invalidate) after the spin. Spin is RELAXED so polling doesn't
// re-invalidate L2 every iteration.
__device__ __forceinline__ void gsync(unsigned* bar, unsigned target) {
    __syncthreads();
    if (threadIdx.x == 0) {
        __threadfence();
        __hip_atomic_fetch_add(bar, 1u, __ATOMIC_RELAXED, __HIP_MEMORY_SCOPE_AGENT);
        while (__hip_atomic_load(bar, __ATOMIC_RELAXED, __HIP_MEMORY_SCOPE_AGENT) < target)
            __builtin_amdgcn_s_sleep(2);
        __threadfence();
    }
    __syncthreads();
}

// ---------- GEMM body (32x128 wave tile): C(bf16) = A(fp32) @ W (+bias) ----------
// No LDS/barriers; Wt (bf16 W^T) is L1/L2-resident; A converted in-register.
__device__ __forceinline__ void gemm_body32(const float* __restrict__ A,
                                            const unsigned short* __restrict__ Wt,
                                            const float* __restrict__ bias,
                                            unsigned short* __restrict__ C, int n, int blk) {
    int tid = threadIdx.x;
    int wave = tid >> 6, lane = tid & 63;
    int lm = lane & 15, g = lane >> 4;
    int m_base = blk * 128 + wave * 32;

    f32x4 acc[2][8];
#pragma unroll
    for (int rt = 0; rt < 2; ++rt)
#pragma unroll
        for (int ct = 0; ct < 8; ++ct) acc[rt][ct] = (f32x4){0.f, 0.f, 0.f, 0.f};

    size_t rowA[2];
    rowA[0] = (size_t)min(m_base + lm, n - 1);
    rowA[1] = (size_t)min(m_base + 16 + lm, n - 1);

#pragma unroll
    for (int kc = 0; kc < 4; ++kc) {
        int k0 = kc * 32 + g * 8;
        bf16x8 a[2];
#pragma unroll
        for (int rt = 0; rt < 2; ++rt) {
            const float* p = A + rowA[rt] * 128 + k0;
            float f[8];
            *(float4*)&f[0] = *(const float4*)p;
            *(float4*)&f[4] = *(const float4*)(p + 4);
            short sv[8];
#pragma unroll
            for (int j = 0; j < 8; ++j) sv[j] = (short)f2bf(f[j]);
            a[rt] = *(bf16x8*)sv;
        }
        bf16x8 b[8];
#pragma unroll
        for (int ct = 0; ct < 8; ++ct)
            b[ct] = *(const bf16x8*)(Wt + (ct * 16 + lm) * 128 + k0);
#pragma unroll
        for (int ct = 0; ct < 8; ++ct) {
            acc[0][ct] = __builtin_amdgcn_mfma_f32_16x16x32_bf16(a[0], b[ct], acc[0][ct], 0, 0, 0);
            acc[1][ct] = __builtin_amdgcn_mfma_f32_16x16x32_bf16(a[1], b[ct], acc[1][ct], 0, 0, 0);
        }
    }

#pragma unroll
    for (int rt = 0; rt < 2; ++rt) {
#pragma unroll
        for (int r = 0; r < 4; ++r) {
            int grow = m_base + rt * 16 + g * 4 + r;
            if (grow < n) {
#pragma unroll
                for (int ct = 0; ct < 8; ++ct) {
                    float v = acc[rt][ct][r];
                    if (bias) v += bias[ct * 16 + lm];
                    C[(size_t)grow * 128 + ct * 16 + lm] = (unsigned short)f2bf(v);
                }
            }
        }
    }
}

// ---------- in-block helper: pre = sum(arr[0..b-1]); optional grand total ----------
__device__ __forceinline__ unsigned blk_prefix(const unsigned* __restrict__ arr, int NB, int b,
                                               unsigned* sc, unsigned* gt) {
    int t = threadIdx.x;
    unsigned s = 0;
    int i0 = t * 4;
#pragma unroll
    for (int k = 0; k < 4; ++k) { int i = i0 + k; if (i < NB) s += arr[i]; }
    sc[t] = s;
    __syncthreads();
    for (int off = 1; off < 256; off <<= 1) {
        unsigned u = (t >= off) ? sc[t - off] : 0;
        __syncthreads();
        sc[t] += u;
        __syncthreads();
    }
    unsigned pre = 0;
    int bq = b >> 2;
    if (bq) pre = sc[bq - 1];
    for (int i = bq * 4; i < b; ++i) pre += arr[i];   // <=3 L2-hot reads
    if (gt) *gt = sc[255];
    unsigned r = pre;
    __syncthreads();                                  // sc reusable after return
    return r;
}

// ---------- aggregation body: one wave per dest node, edge-pair batched gather ----------
template<bool PROJECT>
__device__ __forceinline__ void agg_body(const uint2* __restrict__ tb2,
                                         const int* __restrict__ row_ptr,
                                         const unsigned* __restrict__ edata,
                                         const float* __restrict__ dinv,
                                         const float* __restrict__ bias,
                                         const float* __restrict__ wc2,
                                         void* __restrict__ out, int wid, int lane) {
    int half = lane >> 5;     // which edge of each pair
    int fl   = lane & 31;     // feature group (4 feats)

    float a0 = 0.f, a1 = 0.f, a2 = 0.f, a3 = 0.f;

    int start = row_ptr[wid], end = row_ptr[wid + 1];
    for (int base = start; base < end; base += 64) {
        unsigned ed = edata[base + lane];     // over-read into next buckets is harmless
        int m = end - base; if (m > 64) m = 64;
        int j = 0;
        for (; j + 16 <= m; j += 16) {        // 8 pairs = 16 edges
            unsigned p[8]; uint2 u[8];
#pragma unroll
            for (int k = 0; k < 8; ++k) p[k] = __shfl(ed, j + 2 * k + half);
#pragma unroll
            for (int k = 0; k < 8; ++k) u[k] = tb2[(size_t)(p[k] >> 15) * 32 + fl];
#pragma unroll
            for (int k = 0; k < 8; ++k) {
                float w = __uint_as_float((p[k] & 0x7fffu) << 16);
                a0 += w * bf_lo(u[k].x); a1 += w * bf_hi(u[k].x);
                a2 += w * bf_lo(u[k].y); a3 += w * bf_hi(u[k].y);
            }
        }
        for (; j < m; j += 8) {               // 4 pairs = 8 edges (m is mult of 8)
            unsigned p[4]; uint2 u[4];
#pragma unroll
            for (int k = 0; k < 4; ++k) p[k] = __shfl(ed, j + 2 * k + half);
#pragma unroll
            for (int k = 0; k < 4; ++k) u[k] = tb2[(size_t)(p[k] >> 15) * 32 + fl];
#pragma unroll
            for (int k = 0; k < 4; ++k) {
                float w = __uint_as_float((p[k] & 0x7fffu) << 16);
                a0 += w * bf_lo(u[k].x); a1 += w * bf_hi(u[k].x);
                a2 += w * bf_lo(u[k].y); a3 += w * bf_hi(u[k].y);
            }
        }
    }
    // combine the two halves (lanes l and l^32 end up with identical sums)
    a0 += __shfl_xor(a0, 32); a1 += __shfl_xor(a1, 32);
    a2 += __shfl_xor(a2, 32); a3 += __shfl_xor(a3, 32);

    // self-loop + bias (mirrored across halves)
    float di = dinv[wid];
    float sn = di * di;
    uint2 ts = tb2[(size_t)wid * 32 + fl];
    a0 += sn * bf_lo(ts.x); a1 += sn * bf_hi(ts.x);
    a2 += sn * bf_lo(ts.y); a3 += sn * bf_hi(ts.y);
    float4 bb = ((const float4*)bias)[fl];
    a0 += bb.x; a1 += bb.y; a2 += bb.z; a3 += bb.w;

    if (PROJECT) {
        float4 wv = ((const float4*)wc2)[fl];
        float d = a0 * wv.x + a1 * wv.y + a2 * wv.z + a3 * wv.w;
        if (half) d = 0.f;                    // halves mirror: count once
#pragma unroll
        for (int off = 32; off > 0; off >>= 1) d += __shfl_xor(d, off);
        if (lane == 0) ((float*)out)[wid] = d;     // s[wid], fp32
    } else if (half == 0) {
        float4 o; o.x = a0; o.y = a1; o.z = a2; o.w = a3;
        ((float4*)out)[(size_t)wid * 32 + fl] = o; // fp32 h state
    }
}

// ---------- final-layer body: out[i] = sigmoid( A s + c2 ) ----------
__device__ __forceinline__ void aggfinal_body(const float* __restrict__ s,
                                              const int* __restrict__ row_ptr,
                                              const unsigned* __restrict__ edata,
                                              const float* __restrict__ dinv,
                                              const float* __restrict__ c2,
                                              float* __restrict__ out, int wid, int lane) {
    int start = row_ptr[wid], end = row_ptr[wid + 1];
    float acc = 0.f;
    for (int base = start; base < end; base += 64) {
        int idx = base + lane;
        if (idx < end) {                      // pads have norm=0 -> harmless
            unsigned ed = edata[idx];
            float w = __uint_as_float((ed & 0x7fffu) << 16);
            acc += w * s[ed >> 15];
        }
    }
#pragma unroll
    for (int off = 32; off > 0; off >>= 1) acc += __shfl_xor(acc, off);
    if (lane == 0) {
        float di = dinv[wid];
        float d = acc + di * di * s[wid] + c2[0];
        out[wid] = 1.0f / (1.0f + expf(-d));
    }
}

// ---------- THE mega kernel: 9 phases, one dispatch, manual grid barrier ----------
__global__ __launch_bounds__(256, 4) void mega_kernel(MegaArgs a) {
    __shared__ unsigned shm[1280];            // 5KB: phase-overlaid scratch
    const int b = blockIdx.x, t = threadIdx.x;
    const int G = a.G;
    unsigned tgt = 0;

    // ===== phase 0: bucketCount (blocks [0,NC)) || prep (blocks [NC,NC+130)) =====
    if (b < a.NC) {
        unsigned* cnt = shm;
        for (int i = t; i < a.NB; i += 256) cnt[i] = 0;
        __syncthreads();
        int base = b * 8192;
#pragma unroll 4
        for (int i = 0; i < 32; ++i) {
            int e = base + i * 256 + t;
            if (e < a.E) atomicAdd(&cnt[(unsigned)a.col[e] >> 7], 1u);
        }
        __syncthreads();
        for (int i = t; i < a.NB; i += 256) a.cnt1[(size_t)b * a.NB + i] = cnt[i];
    } else if (b < a.NC + 130) {
        int idx = (b - a.NC) * 256 + t;
        if (idx < 16384) {              // Wt0[nn*128+k] = bf16((W1@Wg0)[k][nn])
            int nn = idx >> 7, k = idx & 127;
            float acc = 0.f;
            for (int j = 0; j < 128; ++j) acc += a.W1[k * 128 + j] * a.Wg[j * 128 + nn];
            a.Wt0[idx] = (unsigned short)f2bf(acc);
        } else if (idx < 32768) {       // Wt1[nn*128+k] = bf16(Wg1[k][nn])
            int tt = idx - 16384;
            int nn = tt >> 7, k = tt & 127;
            a.Wt1[tt] = (unsigned short)f2bf(a.Wg[16384 + k * 128 + nn]);
        } else if (idx < 32896) {       // wc2[k] = sum_j Wg2[k][j] * W2[j]
            int k = idx - 32768;
            float acc = 0.f;
            for (int j = 0; j < 128; ++j) acc += a.Wg[2 * 16384 + k * 128 + j] * a.W2[j];
            a.wc2[k] = acc;
        } else if (idx < 33024) {       // bc0[nn] = sum_j b1[j] * Wg0[j][nn]
            int nn = idx - 32896;
            float acc = 0.f;
            for (int j = 0; j < 128; ++j) acc += a.b1[j] * a.Wg[j * 128 + nn];
            a.bc0[nn] = acc;
        } else if (idx == 33024) {      // c2 = bg2 . W2 + b2
            float acc = a.b2[0];
            for (int j = 0; j < 128; ++j) acc += a.bg[256 + j] * a.W2[j];
            a.c2[0] = acc;
        }
    }
    tgt += G; gsync(a.gbar, tgt);

    // ===== phase 1: colScan (blocks [0,4)) || gemmC0 (blocks [4,4+nGemm)) =====
    if (b < 4) {
        int bk = b * 256 + t;
        if (bk < a.NB) {
            unsigned* cb = a.cnt1;
            unsigned run = 0;
            int j = 0;
            for (; j + 4 <= a.NC; j += 4) {
                size_t i0 = (size_t)j * a.NB + bk;
                unsigned c0 = cb[i0], c1 = cb[i0 + a.NB],
                         c2v = cb[i0 + 2 * (size_t)a.NB], c3 = cb[i0 + 3 * (size_t)a.NB];
                cb[i0] = run;                     run += c0;
                cb[i0 + a.NB] = run;              run += c1;
                cb[i0 + 2 * (size_t)a.NB] = run;  run += c2v;
                cb[i0 + 3 * (size_t)a.NB] = run;  run += c3;
            }
            for (; j < a.NC; ++j) {
                size_t i0 = (size_t)j * a.NB + bk;
                unsigned c = cb[i0]; cb[i0] = run; run += c;
            }
            a.total[bk] = run;
        }
    } else if (b < 4 + a.nGemm) {
        gemm_body32(a.x, a.Wt0, a.bc0, a.tbuf, a.N, b - 4);
    }
    tgt += G; gsync(a.gbar, tgt);

    // ===== phase 2: bucketScatter (blocks [0,NC)) =====
    if (b < a.NC) {
        unsigned* cur = shm;                   // [0,1024)
        unsigned* sc  = shm + 1024;            // [1024,1280)
        int i0 = t * 4;
        unsigned v0 = (i0 < a.NB) ? a.total[i0] : 0;
        unsigned v1 = (i0 + 1 < a.NB) ? a.total[i0 + 1] : 0;
        unsigned v2 = (i0 + 2 < a.NB) ? a.total[i0 + 2] : 0;
        unsigned v3 = (i0 + 3 < a.NB) ? a.total[i0 + 3] : 0;
        sc[t] = v0 + v1 + v2 + v3;
        __syncthreads();
        for (int off = 1; off < 256; off <<= 1) {
            unsigned u = (t >= off) ? sc[t - off] : 0;
            __syncthreads();
            sc[t] += u;
            __syncthreads();
        }
        unsigned bs = (t == 0) ? 0 : sc[t - 1];
        if (i0 < a.NB)     cur[i0]     = bs                + a.cnt1[(size_t)b * a.NB + i0];
        if (i0 + 1 < a.NB) cur[i0 + 1] = bs + v0           + a.cnt1[(size_t)b * a.NB + i0 + 1];
        if (i0 + 2 < a.NB) cur[i0 + 2] = bs + v0 + v1      + a.cnt1[(size_t)b * a.NB + i0 + 2];
        if (i0 + 3 < a.NB) cur[i0 + 3] = bs + v0 + v1 + v2 + a.cnt1[(size_t)b * a.NB + i0 + 3];
        __syncthreads();
        int base = b * 8192;
#pragma unroll 4
        for (int i = 0; i < 32; ++i) {
            int e = base + i * 256 + t;
            if (e < a.E) {
                unsigned c = (unsigned)a.col[e];
                unsigned pos = atomicAdd(&cur[c >> 7], 1u);
                unsigned long long r =
                    ((unsigned long long)(((unsigned)a.row[e] << 7) | (c & 127u)) << 32)
                    | (unsigned long long)__float_as_uint(a.ew[e]);
                a.rec[pos] = r;
            }
        }
    }
    tgt += G; gsync(a.gbar, tgt);

    // ===== phase 3: nodeCount (blocks [0,NB)) =====
    if (b < a.NB) {
        unsigned* lcnt = shm;                  // [0,128)
        unsigned* ldeg = shm + 128;            // [128,256)
        unsigned* sc   = shm + 1024;
        unsigned rstart = blk_prefix(a.total, a.NB, b, sc, nullptr);
        unsigned nb = a.total[b];
        if (t < 128) { lcnt[t] = 0; ldeg[t] = 0; }
        __syncthreads();
        for (unsigned i = t; i < nb; i += 256) {
            unsigned long long r = a.rec[rstart + i];
            unsigned key = (unsigned)(r >> 32);
            unsigned cl = key & 127u;
            float w = __uint_as_float((unsigned)r);
            atomicAdd(&lcnt[cl], 1u);
            atomicAdd(&ldeg[cl], (unsigned)(w * 16777216.0f));   // same truncation as R12
        }
        __syncthreads();
        int node = b * 128 + t;
        unsigned pv = 0;
        if (t < 128 && node < a.N) {
            unsigned c = lcnt[t];
            a.cntg[node] = c;
            a.dinv[node] = rsqrtf(1.0f + (float)ldeg[t] * (1.0f / 16777216.0f));
            pv = (c + 7) & ~7u;
        }
        sc[t] = pv;
        __syncthreads();
        for (int off = 128; off > 0; off >>= 1) {
            if (t < off) sc[t] += sc[t + off];
            __syncthreads();
        }
        if (t == 0) a.padTotal[b] = sc[0];
    }
    tgt += G; gsync(a.gbar, tgt);

    // ===== phase 4: finalize (blocks [0,NB)) =====
    if (b < a.NB) {
        unsigned* curp = shm;                  // [0,128)
        float*    sdv  = (float*)(shm + 128);  // [128,256)
        unsigned* lpre = shm + 256;            // [256,384)
        unsigned* sc   = shm + 1024;
        unsigned gt;
        unsigned rstart = blk_prefix(a.total, a.NB, b, sc, nullptr);
        unsigned nb = a.total[b];
        unsigned ebase = blk_prefix(a.padTotal, a.NB, b, sc, &gt);

        int node = b * 128 + t;
        unsigned c = 0, pv = 0;
        if (t < 128) {
            c = (node < a.N) ? a.cntg[node] : 0;
            pv = (c + 7) & ~7u;
            lpre[t] = pv;
        }
        __syncthreads();
        for (int off = 1; off < 128; off <<= 1) {      // inclusive scan over 128
            unsigned u = (t < 128 && t >= off) ? lpre[t - off] : 0;
            __syncthreads();
            if (t < 128) lpre[t] += u;
            __syncthreads();
        }
        if (t < 128 && node < a.N) {
            unsigned st = ebase + lpre[t] - pv;        // exclusive
            a.row_ptr[node] = (int)st;
            curp[t] = st;
            sdv[t] = a.dinv[node];
            for (unsigned z = c; z < pv; ++z) a.edata[st + z] = 0;   // zero pad slots
        }
        if (b == a.NB - 1 && t == 0) a.row_ptr[a.N] = (int)gt;
        __syncthreads();
        for (unsigned i = t; i < nb; i += 256) {
            unsigned long long r = a.rec[rstart + i];
            unsigned key = (unsigned)(r >> 32);
            unsigned cl = key & 127u, src = key >> 7;
            float w = __uint_as_float((unsigned)r);
            float nrm = a.dinv[src] * w * sdv[cl];     // same multiply order as R12
            unsigned pos = atomicAdd(&curp[cl], 1u);   // LDS cursor
            a.edata[pos] = (src << 15) | (f2bf(nrm) & 0x7fffu);
        }
    }
    tgt += G; gsync(a.gbar, tgt);

    // ===== phase 5: agg0 -> hbuf (fp32), wave-strided =====
    {
        int gw = b * 4 + (t >> 6), lane = t & 63;
        for (int wid = gw; wid < a.N; wid += G * 4)
            agg_body<false>((const uint2*)a.tbuf, a.row_ptr, a.edata, a.dinv,
                            a.bg, nullptr, a.hbuf, wid, lane);
    }
    tgt += G; gsync(a.gbar, tgt);

    // ===== phase 6: gemm1 (hbuf @ Wt1 -> tbuf) =====
    if (b < a.nGemm) gemm_body32(a.hbuf, a.Wt1, nullptr, a.tbuf, a.N, b);
    tgt += G; gsync(a.gbar, tgt);

    // ===== phase 7: agg1 + project -> sbuf =====
    {
        int gw = b * 4 + (t >> 6), lane = t & 63;
        for (int wid = gw; wid < a.N; wid += G * 4)
            agg_body<true>((const uint2*)a.tbuf, a.row_ptr, a.edata, a.dinv,
                           a.bg + 128, a.wc2, a.sbuf, wid, lane);
    }
    tgt += G; gsync(a.gbar, tgt);

    // ===== phase 8: final scalar gather + sigmoid -> out =====
    {
        int gw = b * 4 + (t >> 6), lane = t & 63;
        for (int wid = gw; wid < a.N; wid += G * 4)
            aggfinal_body(a.sbuf, a.row_ptr, a.edata, a.dinv, a.c2, a.out, wid, lane);
    }
}

static inline char* align16(char* p) { return (char*)(((uintptr_t)p + 15) & ~(uintptr_t)15); }

extern "C" void kernel_launch(void* const* d_in, const int* in_sizes, int n_in,
                              void* d_out, int out_size, void* d_ws, size_t ws_size,
                              hipStream_t stream) {
    const float* x  = (const float*)d_in[0];
    const int*   ei = (const int*)d_in[1];   // [2, E] int32
    const float* ea = (const float*)d_in[2]; // [E]
    const float* W1 = (const float*)d_in[3];
    const float* b1 = (const float*)d_in[4];
    const float* Wg = (const float*)d_in[5]; // [3,128,128]
    const float* bg = (const float*)d_in[6]; // [3,128]
    const float* W2 = (const float*)d_in[7]; // [128]
    const float* b2 = (const float*)d_in[8]; // [1]

    const int N = in_sizes[0] / 128;
    const int E = in_sizes[2];
    const int Npad = (N + 127) & ~127;
    const int* row = ei;
    const int* col = ei + E;

    const int NB = (N + 127) >> 7;           // buckets of 128 nodes (782; <=1024)
    const int NC = (E + 8191) >> 13;         // 8192-edge chunks (196)

    // workspace layout (R14 + gbar)
    char* p = (char*)d_ws;
    float*          hbuf = (float*)p;          p += (size_t)Npad * 128 * 4;  // fp32 h state
    unsigned long long* rec = (unsigned long long*)hbuf;  // alias: rec dead before agg0
    unsigned short* tbuf = (unsigned short*)p; p += (size_t)Npad * 128 * 2;  // bf16 messages
    unsigned short* wbuf = (unsigned short*)p; p += 2 * 16384 * 2;           // Wt0, Wt1
    float* bc0 = (float*)p;  p += 128 * 4;
    float* wc2 = (float*)p;  p += 128 * 4;
    float* c2  = (float*)p;  p += 16;
    float* sbuf = (float*)p; p += (size_t)N * 4;
    p = align16(p);
    unsigned* gbar = (unsigned*)p; p += 64;   // grid-barrier counter (memset 0)
    unsigned* cnt1     = (unsigned*)p; p += (size_t)NC * NB * 4;  // counts -> offsets (in place)
    unsigned* total    = (unsigned*)p; p += (size_t)NB * 4;
    unsigned* padTotal = (unsigned*)p; p += (size_t)NB * 4;
    unsigned* cntg     = (unsigned*)p; p += (size_t)N * 4;
    float* dinv   = (float*)p; p += (size_t)N * 4;
    int* row_ptr  = (int*)p;   p += (size_t)(N + 1) * 4; p = align16(p);
    unsigned* edata = (unsigned*)p;                    // E + 7N + 64 padded records

    const int G = 1024;                       // 4 blocks/CU x 256 CUs, co-resident

    MegaArgs margs;
    margs.x = x; margs.row = row; margs.col = col; margs.ew = ea;
    margs.W1 = W1; margs.b1 = b1; margs.Wg = Wg; margs.bg = bg;
    margs.W2 = W2; margs.b2 = b2;
    margs.Wt0 = wbuf; margs.Wt1 = wbuf + 16384;
    margs.bc0 = bc0; margs.wc2 = wc2; margs.c2 = c2;
    margs.tbuf = tbuf; margs.hbuf = hbuf; margs.rec = rec;
    margs.cnt1 = cnt1; margs.total = total; margs.padTotal = padTotal; margs.cntg = cntg;
    margs.dinv = dinv; margs.row_ptr = row_ptr; margs.edata = edata;
    margs.sbuf = sbuf; margs.out = (float*)d_out;
    margs.gbar = gbar;
    margs.N = N; margs.E = E; margs.NB = NB; margs.NC = NC;
    margs.nGemm = Npad / 128; margs.G = G;

    hipMemsetAsync(gbar, 0, 64, stream);      // zero barrier counter (capture-legal)
    mega_kernel<<<dim3(G), dim3(256), 0, stream>>>(margs);
}

// Round 5
// 377.914 us; speedup vs baseline: 3.7572x; 3.7572x over previous
//
#include <hip/hip_runtime.h>
#include <cstdint>
#include <cstddef>

// SimpleGCN: h = x@W1+b1; 3x GCNConv(sym-norm adj w/ self loops); sigmoid(h@W2+b2)
// N=100000, d=128, E=1.6M.
// R17: multi-dispatch again (R16 mega-kernel: 1266us, occupancy-capped +
//   spin-congested -- abandoned). R16 calibration: fixed harness overhead
//   ~150us/iter; graph-replay dispatch boundaries ~free. Budget = ~280us of
//   kernel time (aggs 141, gemms 44, CSR ~90). This round shrinks CSR:
//   - scatterRes (1 kernel) replaces bucketCount+colScan+bucketScatter:
//     fixed bucket capacity CAPB=2560 (mean 2046, +11sigma), per-chunk LDS
//     histogram -> ~780 global range-reservation atomics/chunk (153K total
//     ~7us at the 22G/s memory-side rate) -> LDS-cursor scatter into rec.
//     rec order is replay-nondeterministic (same class as R12 ranks; passed).
//   - countWrite (1 kernel) replaces nodeCount+finalize. Enabled by
//     re-association: sum dinv_s*w*dinv_d*msg = dinv_d * sum w*(dinv_s*msg).
//     edata = (src, bf16(w)) only; dinv_s applied per-edge in agg0 (broadcast
//     load), folded into gemm1 epilogue for agg1, folded into sbuf for final.
//     Per-node segments via int2 rp (bucket-local layout, no global prefix).
// R14: LDS counting sort, zero per-edge global atomics (R13: returning u64
//   atomics execute memory-side regardless of scope; 22G/s floor).
// Algebra (R11): Wc0 = W1@Wg0, wc2 = Wg2@W2, c2 = bg2.W2+b2.
// Determinism: deg via fixed-point u32 adds (order-free); h/s stay fp32.
// rec[] aliases hbuf[] (rec dead before agg0 writes hbuf).

#define CAPB  2560      // rec slots per bucket (u64)
#define EDCAP 3584      // edata words per bucket (2560 + 128*7 pad, rounded)

typedef __attribute__((ext_vector_type(8))) short bf16x8;
typedef __attribute__((ext_vector_type(4))) float f32x4;

// ---------- bf16 helpers (packed dword: low 16 bits = element 0) ----------
__device__ __forceinline__ unsigned f2bf(float f) {      // RNE float->bf16 bits
    unsigned u = __float_as_uint(f);
    u += 0x7fffu + ((u >> 16) & 1u);
    return u >> 16;
}
__device__ __forceinline__ float bf_lo(unsigned p) { return __uint_as_float(p << 16); }
__device__ __forceinline__ float bf_hi(unsigned p) { return __uint_as_float(p & 0xffff0000u); }

// ---------- prep (merged): Wt0 = (W1@Wg0)^T bf16, Wt1 = Wg1^T bf16,
//            wc2 = Wg2@W2, bc0 = b1@Wg0, c2 = bg2.W2+b2, resCur init ----------
__global__ void prep_kernel(const float* __restrict__ W1, const float* __restrict__ Wg,
                            const float* __restrict__ b1, const float* __restrict__ W2,
                            const float* __restrict__ bg, const float* __restrict__ b2,
                            unsigned short* __restrict__ Wt0, unsigned short* __restrict__ Wt1,
                            float* __restrict__ wc2, float* __restrict__ bc0,
                            float* __restrict__ c2, unsigned* __restrict__ resCur, int NB) {
    int idx = blockIdx.x * blockDim.x + threadIdx.x;
    if (idx < NB) resCur[idx] = (unsigned)idx * CAPB;   // bucket reservation cursors
    if (idx < 16384) {              // Wt0[nn*128+k] = bf16((W1@Wg0)[k][nn])
        int nn = idx >> 7, k = idx & 127;
        float acc = 0.f;
        for (int j = 0; j < 128; ++j) acc += W1[k * 128 + j] * Wg[j * 128 + nn];
        Wt0[idx] = (unsigned short)f2bf(acc);
    } else if (idx < 32768) {       // Wt1[nn*128+k] = bf16(Wg1[k][nn])
        int t = idx - 16384;
        int nn = t >> 7, k = t & 127;
        Wt1[t] = (unsigned short)f2bf(Wg[16384 + k * 128 + nn]);
    } else if (idx < 32896) {       // wc2[k] = sum_j Wg2[k][j] * W2[j]
        int k = idx - 32768;
        float acc = 0.f;
        for (int j = 0; j < 128; ++j) acc += Wg[2 * 16384 + k * 128 + j] * W2[j];
        wc2[k] = acc;
    } else if (idx < 33024) {       // bc0[nn] = sum_j b1[j] * Wg0[j][nn]
        int nn = idx - 32896;
        float acc = 0.f;
        for (int j = 0; j < 128; ++j) acc += b1[j] * Wg[j * 128 + nn];
        bc0[nn] = acc;
    } else if (idx == 33024) {      // c2 = bg2 . W2 + b2
        float acc = b2[0];
        for (int j = 0; j < 128; ++j) acc += bg[256 + j] * W2[j];
        c2[0] = acc;
    }
}

// ---------- GEMM body (32x128 wave tile): C(bf16) = (A @ W [*scale] + bias) ----------
// No LDS/barriers; Wt (bf16 W^T) is L1/L2-resident; A converted in-register.
__device__ __forceinline__ void gemm_body32(const float* __restrict__ A,
                                            const unsigned short* __restrict__ Wt,
                                            const float* __restrict__ bias,
                                            const float* __restrict__ scale,
                                            unsigned short* __restrict__ C, int n, int blk) {
    int tid = threadIdx.x;
    int wave = tid >> 6, lane = tid & 63;
    int lm = lane & 15, g = lane >> 4;
    int m_base = blk * 128 + wave * 32;

    f32x4 acc[2][8];
#pragma unroll
    for (int rt = 0; rt < 2; ++rt)
#pragma unroll
        for (int ct = 0; ct < 8; ++ct) acc[rt][ct] = (f32x4){0.f, 0.f, 0.f, 0.f};

    size_t rowA[2];
    rowA[0] = (size_t)min(m_base + lm, n - 1);
    rowA[1] = (size_t)min(m_base + 16 + lm, n - 1);

#pragma unroll
    for (int kc = 0; kc < 4; ++kc) {
        int k0 = kc * 32 + g * 8;
        bf16x8 a[2];
#pragma unroll
        for (int rt = 0; rt < 2; ++rt) {
            const float* p = A + rowA[rt] * 128 + k0;
            float f[8];
            *(float4*)&f[0] = *(const float4*)p;
            *(float4*)&f[4] = *(const float4*)(p + 4);
            short sv[8];
#pragma unroll
            for (int j = 0; j < 8; ++j) sv[j] = (short)f2bf(f[j]);
            a[rt] = *(bf16x8*)sv;
        }
        bf16x8 b[8];
#pragma unroll
        for (int ct = 0; ct < 8; ++ct)
            b[ct] = *(const bf16x8*)(Wt + (ct * 16 + lm) * 128 + k0);
#pragma unroll
        for (int ct = 0; ct < 8; ++ct) {
            acc[0][ct] = __builtin_amdgcn_mfma_f32_16x16x32_bf16(a[0], b[ct], acc[0][ct], 0, 0, 0);
            acc[1][ct] = __builtin_amdgcn_mfma_f32_16x16x32_bf16(a[1], b[ct], acc[1][ct], 0, 0, 0);
        }
    }

#pragma unroll
    for (int rt = 0; rt < 2; ++rt) {
#pragma unroll
        for (int r = 0; r < 4; ++r) {
            int grow = m_base + rt * 16 + g * 4 + r;
            if (grow < n) {
                float sc = scale ? scale[grow] : 1.0f;
#pragma unroll
                for (int ct = 0; ct < 8; ++ct) {
                    float v = acc[rt][ct][r] * sc;
                    if (bias) v += bias[ct * 16 + lm];
                    C[(size_t)grow * 128 + ct * 16 + lm] = (unsigned short)f2bf(v);
                }
            }
        }
    }
}

__global__ __launch_bounds__(256) void gemm_mfma_kernel(const float* __restrict__ A,
                                                        const unsigned short* __restrict__ Wt,
                                                        const float* __restrict__ bias,
                                                        const float* __restrict__ scale,
                                                        unsigned short* __restrict__ C, int n) {
    gemm_body32(A, Wt, bias, scale, C, n, blockIdx.x);
}

// ---------- scatterRes: LDS histogram -> global range reservation -> scatter ----------
// chunk = 8192 edges; bucket = 128 consecutive dst nodes (col>>7).
// rec[b*CAPB ..] = ((src<<7 | col&127) << 32) | f32bits(ew). ~153K global atomics.
__global__ __launch_bounds__(256) void scatterRes_kernel(const int* __restrict__ row,
                                                         const int* __restrict__ col,
                                                         const float* __restrict__ ew,
                                                         unsigned* __restrict__ resCur,
                                                         unsigned long long* __restrict__ rec,
                                                         int E, int NB) {
    __shared__ unsigned cnt[1024];
    int b = blockIdx.x, t = threadIdx.x;
    for (int i = t; i < NB; i += 256) cnt[i] = 0;
    __syncthreads();
    int base = b * 8192;
#pragma unroll 4
    for (int i = 0; i < 32; ++i) {
        int e = base + i * 256 + t;
        if (e < E) atomicAdd(&cnt[(unsigned)col[e] >> 7], 1u);
    }
    __syncthreads();
    for (int i = t; i < NB; i += 256) {
        unsigned c = cnt[i];
        cnt[i] = c ? atomicAdd(&resCur[i], c) : 0u;   // reserve [base, base+c)
    }
    __syncthreads();
#pragma unroll 4
    for (int i = 0; i < 32; ++i) {
        int e = base + i * 256 + t;
        if (e < E) {
            unsigned c = (unsigned)col[e];
            unsigned pos = atomicAdd(&cnt[c >> 7], 1u);          // LDS cursor
            rec[pos] = ((unsigned long long)(((unsigned)row[e] << 7) | (c & 127u)) << 32)
                     | (unsigned long long)__float_as_uint(ew[e]);
        }
    }
}

// ---------- countWrite: per-bucket counts + deg + rp + edata (src, bf16 w) ----------
// Replaces nodeCount+finalize. No cross-bucket dependencies: edata layout is
// bucket-local (bucket b owns words [b*EDCAP, (b+1)*EDCAP)); rp = (start,end).
__global__ __launch_bounds__(256) void countWrite_kernel(const unsigned long long* __restrict__ rec,
                                                         const unsigned* __restrict__ resCur,
                                                         float* __restrict__ dinv,
                                                         int2* __restrict__ rp,
                                                         unsigned* __restrict__ edata,
                                                         int n, int NB) {
    __shared__ unsigned lcnt[128];
    __shared__ unsigned ldeg[128];
    __shared__ unsigned lpre[128];
    __shared__ unsigned curp[128];
    int b = blockIdx.x, t = threadIdx.x;
    unsigned rbase = (unsigned)b * CAPB;
    unsigned tb = min(resCur[b] - rbase, (unsigned)CAPB);   // edges in this bucket
    if (t < 128) { lcnt[t] = 0; ldeg[t] = 0; }
    __syncthreads();
    for (unsigned i = t; i < tb; i += 256) {
        unsigned long long r = rec[rbase + i];
        unsigned cl = (unsigned)(r >> 32) & 127u;
        float w = __uint_as_float((unsigned)r);
        atomicAdd(&lcnt[cl], 1u);
        atomicAdd(&ldeg[cl], (unsigned)(w * 16777216.0f));  // same truncation as R12
    }
    __syncthreads();
    int node = b * 128 + t;
    unsigned c = 0, pv = 0;
    if (t < 128) {
        if (node < n) { c = lcnt[t]; pv = (c + 7) & ~7u; }
        lpre[t] = pv;
    }
    __syncthreads();
    for (int off = 1; off < 128; off <<= 1) {               // inclusive scan over 128
        unsigned u = (t < 128 && t >= off) ? lpre[t - off] : 0;
        __syncthreads();
        if (t < 128) lpre[t] += u;
        __syncthreads();
    }
    if (t < 128 && node < n) {
        unsigned st = (unsigned)b * EDCAP + lpre[t] - pv;   // bucket-local exclusive
        dinv[node] = rsqrtf(1.0f + (float)ldeg[t] * (1.0f / 16777216.0f));
        rp[node] = make_int2((int)st, (int)(st + pv));
        curp[t] = st;
        for (unsigned z = c; z < pv; ++z) edata[st + z] = 0;   // zero pad slots
    }
    __syncthreads();
    for (unsigned i = t; i < tb; i += 256) {
        unsigned long long r = rec[rbase + i];
        unsigned key = (unsigned)(r >> 32);
        unsigned cl = key & 127u, src = key >> 7;
        float w = __uint_as_float((unsigned)r);
        unsigned pos = atomicAdd(&curp[cl], 1u);            // LDS cursor
        edata[pos] = (src << 15) | (f2bf(w) & 0x7fffu);     // raw weight only
    }
}

// ---------- aggregation: one wave per dest node, edge-pair batched gather ----------
// MODE 0 (agg0): input tbuf UNscaled -> apply dinv[src] per edge (broadcast
//   load) and di*(acc + di*self); write fp32 h row.
// MODE 1 (agg1): input tbuf pre-scaled by dinv (gemm1 epilogue) -> plain w;
//   di*(acc + self); project onto wc2; write s_stored = s_true * di (fp32).
template<int MODE>
__global__ __launch_bounds__(256) void aggregate_kernel(const uint2* __restrict__ tb2,
                                                        const int2* __restrict__ rp,
                                                        const unsigned* __restrict__ edata,
                                                        const float* __restrict__ dinv,
                                                        const float* __restrict__ bias,
                                                        const float* __restrict__ wc2,
                                                        void* __restrict__ out, int n) {
    int wid  = (int)((blockIdx.x * (size_t)blockDim.x + threadIdx.x) >> 6);
    int lane = threadIdx.x & 63;
    if (wid >= n) return;
    int half = lane >> 5;     // which edge of each pair
    int fl   = lane & 31;     // feature group (4 feats)

    float a0 = 0.f, a1 = 0.f, a2 = 0.f, a3 = 0.f;

    int2 seg = rp[wid];
    int start = seg.x, end = seg.y;
    for (int base = start; base < end; base += 64) {
        unsigned ed = edata[base + lane];     // over-read into pad guard is harmless
        int m = end - base; if (m > 64) m = 64;
        int j = 0;
        for (; j + 16 <= m; j += 16) {        // 8 pairs = 16 edges
            unsigned p[8]; uint2 u[8]; float dv[8];
#pragma unroll
            for (int k = 0; k < 8; ++k) p[k] = __shfl(ed, j + 2 * k + half);
#pragma unroll
            for (int k = 0; k < 8; ++k) {
                unsigned s = p[k] >> 15;
                u[k] = tb2[(size_t)s * 32 + fl];
                if (MODE == 0) dv[k] = dinv[s];            // 32-lane broadcast
            }
#pragma unroll
            for (int k = 0; k < 8; ++k) {
                float w = __uint_as_float((p[k] & 0x7fffu) << 16);
                if (MODE == 0) w *= dv[k];
                a0 += w * bf_lo(u[k].x); a1 += w * bf_hi(u[k].x);
                a2 += w * bf_lo(u[k].y); a3 += w * bf_hi(u[k].y);
            }
        }
        for (; j < m; j += 8) {               // 4 pairs = 8 edges (m is mult of 8)
            unsigned p[4]; uint2 u[4]; float dv[4];
#pragma unroll
            for (int k = 0; k < 4; ++k) p[k] = __shfl(ed, j + 2 * k + half);
#pragma unroll
            for (int k = 0; k < 4; ++k) {
                unsigned s = p[k] >> 15;
                u[k] = tb2[(size_t)s * 32 + fl];
                if (MODE == 0) dv[k] = dinv[s];
            }
#pragma unroll
            for (int k = 0; k < 4; ++k) {
                float w = __uint_as_float((p[k] & 0x7fffu) << 16);
                if (MODE == 0) w *= dv[k];
                a0 += w * bf_lo(u[k].x); a1 += w * bf_hi(u[k].x);
                a2 += w * bf_lo(u[k].y); a3 += w * bf_hi(u[k].y);
            }
        }
    }
    // combine the two halves (lanes l and l^32 end up with identical sums)
    a0 += __shfl_xor(a0, 32); a1 += __shfl_xor(a1, 32);
    a2 += __shfl_xor(a2, 32); a3 += __shfl_xor(a3, 32);

    // self-loop + bias (mirrored across halves)
    float di = dinv[wid];
    uint2 ts = tb2[(size_t)wid * 32 + fl];
    float s0 = bf_lo(ts.x), s1 = bf_hi(ts.x), s2 = bf_lo(ts.y), s3 = bf_hi(ts.y);
    if (MODE == 0) { s0 *= di; s1 *= di; s2 *= di; s3 *= di; }   // unscaled input
    float4 bb = ((const float4*)bias)[fl];
    a0 = di * (a0 + s0) + bb.x; a1 = di * (a1 + s1) + bb.y;
    a2 = di * (a2 + s2) + bb.z; a3 = di * (a3 + s3) + bb.w;

    if (MODE == 1) {
        float4 wv = ((const float4*)wc2)[fl];
        float d = a0 * wv.x + a1 * wv.y + a2 * wv.z + a3 * wv.w;
        if (half) d = 0.f;                    // halves mirror: count once
#pragma unroll
        for (int off = 32; off > 0; off >>= 1) d += __shfl_xor(d, off);
        if (lane == 0) ((float*)out)[wid] = d * di;   // s_stored = s_true * dinv
    } else if (half == 0) {
        float4 o; o.x = a0; o.y = a1; o.z = a2; o.w = a3;
        ((float4*)out)[(size_t)wid * 32 + fl] = o;    // fp32 h state
    }
}

// ---------- final: scalar gather  out[i] = sigmoid( di*(acc + s[i]) + c2 ) ----------
// s is pre-scaled by dinv (s_stored); self-loop term di*s_stored[i] = di^2*s_true.
__global__ __launch_bounds__(256) void aggFinal_kernel(const float* __restrict__ s,
                                                       const int2* __restrict__ rp,
                                                       const unsigned* __restrict__ edata,
                                                       const float* __restrict__ dinv,
                                                       const float* __restrict__ c2,
                                                       float* __restrict__ out, int n) {
    int wid  = (int)((blockIdx.x * (size_t)blockDim.x + threadIdx.x) >> 6);
    int lane = threadIdx.x & 63;
    if (wid >= n) return;
    int2 seg = rp[wid];
    int start = seg.x, end = seg.y;
    float acc = 0.f;
    for (int base = start; base < end; base += 64) {
        int idx = base + lane;
        if (idx < end) {                      // pads have w=0 -> harmless
            unsigned ed = edata[idx];
            float w = __uint_as_float((ed & 0x7fffu) << 16);
            acc += w * s[ed >> 15];
        }
    }
#pragma unroll
    for (int off = 32; off > 0; off >>= 1) acc += __shfl_xor(acc, off);
    if (lane == 0) {
        float di = dinv[wid];
        float d = di * (acc + s[wid]) + c2[0];
        out[wid] = 1.0f / (1.0f + expf(-d));
    }
}

static inline char* align16(char* p) { return (char*)(((uintptr_t)p + 15) & ~(uintptr_t)15); }

extern "C" void kernel_launch(void* const* d_in, const int* in_sizes, int n_in,
                              void* d_out, int out_size, void* d_ws, size_t ws_size,
                              hipStream_t stream) {
    const float* x  = (const float*)d_in[0];
    const int*   ei = (const int*)d_in[1];   // [2, E] int32
    const float* ea = (const float*)d_in[2]; // [E]
    const float* W1 = (const float*)d_in[3];
    const float* b1 = (const float*)d_in[4];
    const float* Wg = (const float*)d_in[5]; // [3,128,128]
    const float* bg = (const float*)d_in[6]; // [3,128]
    const float* W2 = (const float*)d_in[7]; // [128]
    const float* b2 = (const float*)d_in[8]; // [1]

    const int N = in_sizes[0] / 128;
    const int E = in_sizes[2];
    const int Npad = (N + 127) & ~127;
    const int* row = ei;
    const int* col = ei + E;

    const int NB = (N + 127) >> 7;           // buckets of 128 nodes (782)
    const int NC = (E + 8191) >> 13;         // 8192-edge chunks (196)

    // workspace layout
    char* p = (char*)d_ws;
    float*          hbuf = (float*)p;          p += (size_t)Npad * 128 * 4;  // fp32 h state
    unsigned long long* rec = (unsigned long long*)hbuf;  // alias: NB*CAPB*8 = 16MB <= 51MB
    unsigned short* tbuf = (unsigned short*)p; p += (size_t)Npad * 128 * 2;  // bf16 messages
    unsigned short* wbuf = (unsigned short*)p; p += 2 * 16384 * 2;           // Wt0, Wt1
    float* bc0 = (float*)p;  p += 128 * 4;
    float* wc2 = (float*)p;  p += 128 * 4;
    float* c2  = (float*)p;  p += 16;
    float* sbuf = (float*)p; p += (size_t)N * 4;
    p = align16(p);
    unsigned* resCur = (unsigned*)p; p += (size_t)NB * 4; p = align16(p);
    float* dinv = (float*)p; p += (size_t)N * 4;
    int2* rp    = (int2*)p;  p += (size_t)N * 8; p = align16(p);
    unsigned* edata = (unsigned*)p;            // NB*EDCAP words + guard (~11.2MB)

    dim3 b256(256);
    int nGemm = Npad / 128;                  // 782
    int nPrep = (33025 + 255) / 256;         // 130 (covers NB init too)
    int wave_blocks = (int)(((size_t)N * 64 + 255) / 256);

    // D1: weights prep + reservation cursors
    prep_kernel<<<nPrep, b256, 0, stream>>>(W1, Wg, b1, W2, bg, b2,
                                            wbuf, wbuf + 16384, wc2, bc0, c2, resCur, NB);
    // D2: bucket-sort edges into rec (one kernel, ~153K reservation atomics)
    scatterRes_kernel<<<NC, b256, 0, stream>>>(row, col, ea, resCur, rec, E, NB);
    // D3: per-bucket counts + deg/dinv + rp + edata(src, bf16 w)
    countWrite_kernel<<<NB, b256, 0, stream>>>(rec, resCur, dinv, rp, edata, N, NB);
    // D4: layer-0 GEMM (x @ Wc0 + bc0 -> tbuf, unscaled)
    gemm_mfma_kernel<<<nGemm, b256, 0, stream>>>(x, wbuf, bc0, nullptr, tbuf, N);
    // D5: agg0 (dinv[src] per edge) -> hbuf fp32
    aggregate_kernel<0><<<wave_blocks, b256, 0, stream>>>(
        (const uint2*)tbuf, rp, edata, dinv, bg, nullptr, hbuf, N);
    // D6: gemm1 (hbuf @ Wt1, epilogue *dinv -> pre-scaled tbuf)
    gemm_mfma_kernel<<<nGemm, b256, 0, stream>>>(hbuf, wbuf + 16384, nullptr, dinv, tbuf, N);
    // D7: agg1 + project -> sbuf (pre-scaled by dinv)
    aggregate_kernel<1><<<wave_blocks, b256, 0, stream>>>(
        (const uint2*)tbuf, rp, edata, dinv, bg + 128, wc2, sbuf, N);
    // D8: final scalar gather + sigmoid
    aggFinal_kernel<<<wave_blocks, b256, 0, stream>>>(sbuf, rp, edata, dinv, c2,
                                                      (float*)d_out, N);
}

// Round 6
// 287.827 us; speedup vs baseline: 4.9331x; 1.3130x over previous
//
#include <hip/hip_runtime.h>
#include <cstdint>
#include <cstddef>

// SimpleGCN: h = x@W1+b1; 3x GCNConv(sym-norm adj w/ self loops); sigmoid(h@W2+b2)
// N=100000, d=128, E=1.6M.
// R18 = R17 + full back-half algebraic collapse + scatterRes occupancy fix.
//   Collapse: logit = A@s + c2, s = A@q + sb, q_i = h1_i . wv, where
//     wv = Wg1@Wg2@W2 (prep), sb = bg1.wc2, c2 = bg2.W2+b2.
//   So gemm1 and the 128-dim agg1 are GONE; agg0 becomes aggQ (projects its
//   in-register h1 row onto wv -> scalar q, writes 0.4MB instead of 50MB).
//   tbuf pre-scaled by dinv in gemm0 epilogue (v=(acc+bias)*dinv): gather
//   inner loop has no per-edge dinv load; self term = td_i directly.
//   scatterRes: 1024 thr/block (R17: 7% occupancy, 1% VALU -> latency-starved
//   at 196x256; 16 waves/CU now).
// R17: scatterRes (reservation sort, CAPB=2560) + countWrite (bucket-local
//   CSR, int2 rp). R16 calibration: ~150us fixed harness overhead; dispatch
//   boundaries ~free under graph replay.
// R14/R13: zero per-edge global atomics (returning u64 atomics execute
//   memory-side regardless of scope; 22G/s floor).
// Determinism: deg via fixed-point u32 adds; q/s/logit stay fp32 (no bf16
//   re-quantization of order-dependent sums); bf16 only on deterministic
//   GEMM/prep outputs.

#define CAPB  2560      // rec slots per bucket (u64)
#define EDCAP 3584      // edata words per bucket (2560 + 128*7 pad, rounded)

typedef __attribute__((ext_vector_type(8))) short bf16x8;
typedef __attribute__((ext_vector_type(4))) float f32x4;

// ---------- bf16 helpers (packed dword: low 16 bits = element 0) ----------
__device__ __forceinline__ unsigned f2bf(float f) {      // RNE float->bf16 bits
    unsigned u = __float_as_uint(f);
    u += 0x7fffu + ((u >> 16) & 1u);
    return u >> 16;
}
__device__ __forceinline__ float bf_lo(unsigned p) { return __uint_as_float(p << 16); }
__device__ __forceinline__ float bf_hi(unsigned p) { return __uint_as_float(p & 0xffff0000u); }

// ---------- prep1: Wt0 = (W1@Wg0)^T bf16, wc2 = Wg2@W2, bc0 = b1@Wg0,
//            c2 = bg2.W2+b2, resCur init ----------
__global__ void prep1_kernel(const float* __restrict__ W1, const float* __restrict__ Wg,
                             const float* __restrict__ b1, const float* __restrict__ W2,
                             const float* __restrict__ bg, const float* __restrict__ b2,
                             unsigned short* __restrict__ Wt0, float* __restrict__ wc2,
                             float* __restrict__ bc0, float* __restrict__ c2,
                             unsigned* __restrict__ resCur, int NB) {
    int idx = blockIdx.x * blockDim.x + threadIdx.x;
    if (idx < NB) resCur[idx] = (unsigned)idx * CAPB;   // bucket reservation cursors
    if (idx < 16384) {              // Wt0[nn*128+k] = bf16((W1@Wg0)[k][nn])
        int nn = idx >> 7, k = idx & 127;
        float acc = 0.f;
        for (int j = 0; j < 128; ++j) acc += W1[k * 128 + j] * Wg[j * 128 + nn];
        Wt0[idx] = (unsigned short)f2bf(acc);
    } else if (idx < 16512) {       // wc2[k] = sum_j Wg2[k][j] * W2[j]
        int k = idx - 16384;
        float acc = 0.f;
        for (int j = 0; j < 128; ++j) acc += Wg[2 * 16384 + k * 128 + j] * W2[j];
        wc2[k] = acc;
    } else if (idx < 16640) {       // bc0[nn] = sum_j b1[j] * Wg0[j][nn]
        int nn = idx - 16512;
        float acc = 0.f;
        for (int j = 0; j < 128; ++j) acc += b1[j] * Wg[j * 128 + nn];
        bc0[nn] = acc;
    } else if (idx == 16640) {      // c2 = bg2 . W2 + b2
        float acc = b2[0];
        for (int j = 0; j < 128; ++j) acc += bg[256 + j] * W2[j];
        c2[0] = acc;
    }
}

// ---------- prep2 (needs wc2): wv = Wg1@wc2, sb = bg1.wc2 ----------
__global__ void prep2_kernel(const float* __restrict__ Wg, const float* __restrict__ bg,
                             const float* __restrict__ wc2,
                             float* __restrict__ wv, float* __restrict__ sbp) {
    int k = threadIdx.x;
    if (k < 128) {
        float acc = 0.f;
        for (int j = 0; j < 128; ++j) acc += Wg[16384 + k * 128 + j] * wc2[j];
        wv[k] = acc;
    }
    if (k == 0) {
        float s = 0.f;
        for (int j = 0; j < 128; ++j) s += bg[128 + j] * wc2[j];
        sbp[0] = s;
    }
}

// ---------- GEMM body (32x128 wave tile): C(bf16) = (A@W + bias) * scale ----------
// No LDS/barriers; Wt (bf16 W^T) is L1/L2-resident; A converted in-register.
__device__ __forceinline__ void gemm_body32(const float* __restrict__ A,
                                            const unsigned short* __restrict__ Wt,
                                            const float* __restrict__ bias,
                                            const float* __restrict__ scale,
                                            unsigned short* __restrict__ C, int n, int blk) {
    int tid = threadIdx.x;
    int wave = tid >> 6, lane = tid & 63;
    int lm = lane & 15, g = lane >> 4;
    int m_base = blk * 128 + wave * 32;

    f32x4 acc[2][8];
#pragma unroll
    for (int rt = 0; rt < 2; ++rt)
#pragma unroll
        for (int ct = 0; ct < 8; ++ct) acc[rt][ct] = (f32x4){0.f, 0.f, 0.f, 0.f};

    size_t rowA[2];
    rowA[0] = (size_t)min(m_base + lm, n - 1);
    rowA[1] = (size_t)min(m_base + 16 + lm, n - 1);

#pragma unroll
    for (int kc = 0; kc < 4; ++kc) {
        int k0 = kc * 32 + g * 8;
        bf16x8 a[2];
#pragma unroll
        for (int rt = 0; rt < 2; ++rt) {
            const float* p = A + rowA[rt] * 128 + k0;
            float f[8];
            *(float4*)&f[0] = *(const float4*)p;
            *(float4*)&f[4] = *(const float4*)(p + 4);
            short sv[8];
#pragma unroll
            for (int j = 0; j < 8; ++j) sv[j] = (short)f2bf(f[j]);
            a[rt] = *(bf16x8*)sv;
        }
        bf16x8 b[8];
#pragma unroll
        for (int ct = 0; ct < 8; ++ct)
            b[ct] = *(const bf16x8*)(Wt + (ct * 16 + lm) * 128 + k0);
#pragma unroll
        for (int ct = 0; ct < 8; ++ct) {
            acc[0][ct] = __builtin_amdgcn_mfma_f32_16x16x32_bf16(a[0], b[ct], acc[0][ct], 0, 0, 0);
            acc[1][ct] = __builtin_amdgcn_mfma_f32_16x16x32_bf16(a[1], b[ct], acc[1][ct], 0, 0, 0);
        }
    }

#pragma unroll
    for (int rt = 0; rt < 2; ++rt) {
#pragma unroll
        for (int r = 0; r < 4; ++r) {
            int grow = m_base + rt * 16 + g * 4 + r;
            if (grow < n) {
                float sc = scale ? scale[grow] : 1.0f;
#pragma unroll
                for (int ct = 0; ct < 8; ++ct) {
                    float v = acc[rt][ct][r];
                    if (bias) v += bias[ct * 16 + lm];
                    v *= sc;
                    C[(size_t)grow * 128 + ct * 16 + lm] = (unsigned short)f2bf(v);
                }
            }
        }
    }
}

__global__ __launch_bounds__(256) void gemm_mfma_kernel(const float* __restrict__ A,
                                                        const unsigned short* __restrict__ Wt,
                                                        const float* __restrict__ bias,
                                                        const float* __restrict__ scale,
                                                        unsigned short* __restrict__ C, int n) {
    gemm_body32(A, Wt, bias, scale, C, n, blockIdx.x);
}

// ---------- scatterRes: LDS histogram -> global range reservation -> scatter ----------
// chunk = 8192 edges; 1024 threads (8 edges/thread); bucket = 128 dst nodes.
// rec[b*CAPB ..] = ((src<<7 | col&127) << 32) | f32bits(ew). ~153K global atomics.
__global__ __launch_bounds__(1024) void scatterRes_kernel(const int* __restrict__ row,
                                                          const int* __restrict__ col,
                                                          const float* __restrict__ ew,
                                                          unsigned* __restrict__ resCur,
                                                          unsigned long long* __restrict__ rec,
                                                          int E, int NB) {
    __shared__ unsigned cnt[1024];
    int b = blockIdx.x, t = threadIdx.x;
    cnt[t] = 0;
    __syncthreads();
    int base = b * 8192;
#pragma unroll
    for (int i = 0; i < 8; ++i) {
        int e = base + i * 1024 + t;
        if (e < E) atomicAdd(&cnt[(unsigned)col[e] >> 7], 1u);
    }
    __syncthreads();
    if (t < NB) {
        unsigned c = cnt[t];
        cnt[t] = c ? atomicAdd(&resCur[t], c) : 0u;   // reserve [base, base+c)
    }
    __syncthreads();
#pragma unroll
    for (int i = 0; i < 8; ++i) {
        int e = base + i * 1024 + t;
        if (e < E) {
            unsigned c = (unsigned)col[e];
            unsigned pos = atomicAdd(&cnt[c >> 7], 1u);          // LDS cursor
            rec[pos] = ((unsigned long long)(((unsigned)row[e] << 7) | (c & 127u)) << 32)
                     | (unsigned long long)__float_as_uint(ew[e]);
        }
    }
}

// ---------- countWrite: per-bucket counts + deg + rp + edata (src, bf16 w) ----------
// Bucket-local edata layout (bucket b owns words [b*EDCAP,(b+1)*EDCAP)); rp=(start,end).
__global__ __launch_bounds__(256) void countWrite_kernel(const unsigned long long* __restrict__ rec,
                                                         const unsigned* __restrict__ resCur,
                                                         float* __restrict__ dinv,
                                                         int2* __restrict__ rp,
                                                         unsigned* __restrict__ edata,
                                                         int n, int NB) {
    __shared__ unsigned lcnt[128];
    __shared__ unsigned ldeg[128];
    __shared__ unsigned lpre[128];
    __shared__ unsigned curp[128];
    int b = blockIdx.x, t = threadIdx.x;
    unsigned rbase = (unsigned)b * CAPB;
    unsigned tb = min(resCur[b] - rbase, (unsigned)CAPB);   // edges in this bucket
    if (t < 128) { lcnt[t] = 0; ldeg[t] = 0; }
    __syncthreads();
    for (unsigned i = t; i < tb; i += 256) {
        unsigned long long r = rec[rbase + i];
        unsigned cl = (unsigned)(r >> 32) & 127u;
        float w = __uint_as_float((unsigned)r);
        atomicAdd(&lcnt[cl], 1u);
        atomicAdd(&ldeg[cl], (unsigned)(w * 16777216.0f));  // same truncation as R12
    }
    __syncthreads();
    int node = b * 128 + t;
    unsigned c = 0, pv = 0;
    if (t < 128) {
        if (node < n) { c = lcnt[t]; pv = (c + 7) & ~7u; }
        lpre[t] = pv;
    }
    __syncthreads();
    for (int off = 1; off < 128; off <<= 1) {               // inclusive scan over 128
        unsigned u = (t < 128 && t >= off) ? lpre[t - off] : 0;
        __syncthreads();
        if (t < 128) lpre[t] += u;
        __syncthreads();
    }
    if (t < 128 && node < n) {
        unsigned st = (unsigned)b * EDCAP + lpre[t] - pv;   // bucket-local exclusive
        dinv[node] = rsqrtf(1.0f + (float)ldeg[t] * (1.0f / 16777216.0f));
        rp[node] = make_int2((int)st, (int)(st + pv));
        curp[t] = st;
        for (unsigned z = c; z < pv; ++z) edata[st + z] = 0;   // zero pad slots
    }
    __syncthreads();
    for (unsigned i = t; i < tb; i += 256) {
        unsigned long long r = rec[rbase + i];
        unsigned key = (unsigned)(r >> 32);
        unsigned cl = key & 127u, src = key >> 7;
        float w = __uint_as_float((unsigned)r);
        unsigned pos = atomicAdd(&curp[cl], 1u);            // LDS cursor
        edata[pos] = (src << 15) | (f2bf(w) & 0x7fffu);     // raw weight only
    }
}

// ---------- aggQ: one wave per dest node; gather td rows, project onto wv ----------
// tbuf is pre-scaled: td_j = dinv_j * t0_j. h1_i = di*(sum w*td_j + td_i) + bg0.
// q_i = h1_i . wv; write qs[i] = q_i * di (pre-scaled for next scalar gather).
__global__ __launch_bounds__(256) void aggQ_kernel(const uint2* __restrict__ tb2,
                                                   const int2* __restrict__ rp,
                                                   const unsigned* __restrict__ edata,
                                                   const float* __restrict__ dinv,
                                                   const float* __restrict__ bias,
                                                   const float* __restrict__ wv,
                                                   float* __restrict__ qs, int n) {
    int wid  = (int)((blockIdx.x * (size_t)blockDim.x + threadIdx.x) >> 6);
    int lane = threadIdx.x & 63;
    if (wid >= n) return;
    int half = lane >> 5;     // which edge of each pair
    int fl   = lane & 31;     // feature group (4 feats)

    float a0 = 0.f, a1 = 0.f, a2 = 0.f, a3 = 0.f;

    int2 seg = rp[wid];
    int start = seg.x, end = seg.y;
    for (int base = start; base < end; base += 64) {
        unsigned ed = edata[base + lane];     // over-read within bucket is harmless
        int m = end - base; if (m > 64) m = 64;
        int j = 0;
        for (; j + 16 <= m; j += 16) {        // 8 pairs = 16 edges
            unsigned p[8]; uint2 u[8];
#pragma unroll
            for (int k = 0; k < 8; ++k) p[k] = __shfl(ed, j + 2 * k + half);
#pragma unroll
            for (int k = 0; k < 8; ++k) u[k] = tb2[(size_t)(p[k] >> 15) * 32 + fl];
#pragma unroll
            for (int k = 0; k < 8; ++k) {
                float w = __uint_as_float((p[k] & 0x7fffu) << 16);
                a0 += w * bf_lo(u[k].x); a1 += w * bf_hi(u[k].x);
                a2 += w * bf_lo(u[k].y); a3 += w * bf_hi(u[k].y);
            }
        }
        for (; j < m; j += 8) {               // 4 pairs = 8 edges (m is mult of 8)
            unsigned p[4]; uint2 u[4];
#pragma unroll
            for (int k = 0; k < 4; ++k) p[k] = __shfl(ed, j + 2 * k + half);
#pragma unroll
            for (int k = 0; k < 4; ++k) u[k] = tb2[(size_t)(p[k] >> 15) * 32 + fl];
#pragma unroll
            for (int k = 0; k < 4; ++k) {
                float w = __uint_as_float((p[k] & 0x7fffu) << 16);
                a0 += w * bf_lo(u[k].x); a1 += w * bf_hi(u[k].x);
                a2 += w * bf_lo(u[k].y); a3 += w * bf_hi(u[k].y);
            }
        }
    }
    // combine the two halves (lanes l and l^32 end up with identical sums)
    a0 += __shfl_xor(a0, 32); a1 += __shfl_xor(a1, 32);
    a2 += __shfl_xor(a2, 32); a3 += __shfl_xor(a3, 32);

    // self-loop (td_i, pre-scaled) + bias -> h1 components
    float di = dinv[wid];
    uint2 ts = tb2[(size_t)wid * 32 + fl];
    float4 bb = ((const float4*)bias)[fl];
    a0 = di * (a0 + bf_lo(ts.x)) + bb.x;
    a1 = di * (a1 + bf_hi(ts.x)) + bb.y;
    a2 = di * (a2 + bf_lo(ts.y)) + bb.z;
    a3 = di * (a3 + bf_hi(ts.y)) + bb.w;

    // q = h1 . wv  (reduce over 32 feature lanes; halves mirrored)
    float4 w4 = ((const float4*)wv)[fl];
    float qp = a0 * w4.x + a1 * w4.y + a2 * w4.z + a3 * w4.w;
#pragma unroll
    for (int off = 16; off > 0; off >>= 1) qp += __shfl_xor(qp, off);
    if (lane == 0) qs[wid] = qp * di;
}

// ---------- scalar aggregation: v_out = di*(acc + vals[i]) + K ----------
// vals pre-scaled by dinv. FINAL=0: write v_out*di (pre-scale for next hop).
// FINAL=1: write sigmoid(v_out).
template<int FINAL>
__global__ __launch_bounds__(256) void scalarAgg_kernel(const float* __restrict__ vals,
                                                        const int2* __restrict__ rp,
                                                        const unsigned* __restrict__ edata,
                                                        const float* __restrict__ dinv,
                                                        const float* __restrict__ kc,
                                                        float* __restrict__ out, int n) {
    int wid  = (int)((blockIdx.x * (size_t)blockDim.x + threadIdx.x) >> 6);
    int lane = threadIdx.x & 63;
    if (wid >= n) return;
    int2 seg = rp[wid];
    int start = seg.x, end = seg.y;
    float acc = 0.f;
    for (int base = start; base < end; base += 64) {
        int idx = base + lane;
        if (idx < end) {                      // pads have w=0 -> harmless
            unsigned ed = edata[idx];
            float w = __uint_as_float((ed & 0x7fffu) << 16);
            acc += w * vals[ed >> 15];
        }
    }
#pragma unroll
    for (int off = 32; off > 0; off >>= 1) acc += __shfl_xor(acc, off);
    if (lane == 0) {
        float di = dinv[wid];
        float d = di * (acc + vals[wid]) + kc[0];
        out[wid] = FINAL ? 1.0f / (1.0f + expf(-d)) : d * di;
    }
}

static inline char* align16(char* p) { return (char*)(((uintptr_t)p + 15) & ~(uintptr_t)15); }

extern "C" void kernel_launch(void* const* d_in, const int* in_sizes, int n_in,
                              void* d_out, int out_size, void* d_ws, size_t ws_size,
                              hipStream_t stream) {
    const float* x  = (const float*)d_in[0];
    const int*   ei = (const int*)d_in[1];   // [2, E] int32
    const float* ea = (const float*)d_in[2]; // [E]
    const float* W1 = (const float*)d_in[3];
    const float* b1 = (const float*)d_in[4];
    const float* Wg = (const float*)d_in[5]; // [3,128,128]
    const float* bg = (const float*)d_in[6]; // [3,128]
    const float* W2 = (const float*)d_in[7]; // [128]
    const float* b2 = (const float*)d_in[8]; // [1]

    const int N = in_sizes[0] / 128;
    const int E = in_sizes[2];
    const int Npad = (N + 127) & ~127;
    const int* row = ei;
    const int* col = ei + E;

    const int NB = (N + 127) >> 7;           // buckets of 128 nodes (782)
    const int NC = (E + 8191) >> 13;         // 8192-edge chunks (196)

    // workspace layout
    char* p = (char*)d_ws;
    unsigned long long* rec = (unsigned long long*)p; p += (size_t)NB * CAPB * 8; // 16MB
    unsigned short* tbuf = (unsigned short*)p; p += (size_t)Npad * 128 * 2;  // bf16 td rows
    unsigned short* wbuf = (unsigned short*)p; p += 16384 * 2;               // Wt0
    float* bc0 = (float*)p;  p += 128 * 4;
    float* wc2 = (float*)p;  p += 128 * 4;
    float* wv  = (float*)p;  p += 128 * 4;
    float* c2  = (float*)p;  p += 16;
    float* sbp = (float*)p;  p += 16;
    float* qs  = (float*)p;  p += (size_t)N * 4;
    float* ss  = (float*)p;  p += (size_t)N * 4;
    p = align16(p);
    unsigned* resCur = (unsigned*)p; p += (size_t)NB * 4; p = align16(p);
    float* dinv = (float*)p; p += (size_t)N * 4;
    int2* rp    = (int2*)p;  p += (size_t)N * 8; p = align16(p);
    unsigned* edata = (unsigned*)p;            // NB*EDCAP words + guard (~11.2MB)

    dim3 b256(256);
    int nGemm = Npad / 128;                  // 782
    int nPrep = (16641 + 255) / 256;         // 66
    int wave_blocks = (int)(((size_t)N * 64 + 255) / 256);

    // D1: weights prep (Wt0, wc2, bc0, c2) + reservation cursors
    prep1_kernel<<<nPrep, b256, 0, stream>>>(W1, Wg, b1, W2, bg, b2,
                                             wbuf, wc2, bc0, c2, resCur, NB);
    // D2: wv = Wg1@wc2, sb = bg1.wc2
    prep2_kernel<<<1, dim3(128), 0, stream>>>(Wg, bg, wc2, wv, sbp);
    // D3: bucket-sort edges into rec (1024 thr: R17 was latency-starved at 7% occ)
    scatterRes_kernel<<<NC, dim3(1024), 0, stream>>>(row, col, ea, resCur, rec, E, NB);
    // D4: per-bucket counts + deg/dinv + rp + edata(src, bf16 w)
    countWrite_kernel<<<NB, b256, 0, stream>>>(rec, resCur, dinv, rp, edata, N, NB);
    // D5: layer-0 GEMM: td = dinv * (x @ Wc0 + bc0) -> tbuf (pre-scaled)
    gemm_mfma_kernel<<<nGemm, b256, 0, stream>>>(x, wbuf, bc0, dinv, tbuf, N);
    // D6: aggQ: gather td rows -> h1 (in-reg) -> q = h1.wv -> qs = q*dinv
    aggQ_kernel<<<wave_blocks, b256, 0, stream>>>(
        (const uint2*)tbuf, rp, edata, dinv, bg, wv, qs, N);
    // D7: s = A@q + sb (scalar gather); store ss = s*dinv
    scalarAgg_kernel<0><<<wave_blocks, b256, 0, stream>>>(qs, rp, edata, dinv, sbp, ss, N);
    // D8: logit = A@s + c2; out = sigmoid(logit)
    scalarAgg_kernel<1><<<wave_blocks, b256, 0, stream>>>(ss, rp, edata, dinv, c2,
                                                          (float*)d_out, N);
}

// Round 7
// 222.684 us; speedup vs baseline: 6.3762x; 1.2925x over previous
//
#include <hip/hip_runtime.h>
#include <cstdint>
#include <cstddef>

// SimpleGCN: h = x@W1+b1; 3x GCNConv(sym-norm adj w/ self loops); sigmoid(h@W2+b2)
// N=100000, d=128, E=1.6M.
// R19 = TOTAL algebraic collapse. The reference has NO nonlinearity between
//   layers -> everything from x to the logit is linear. Projection onto the
//   output vector commutes with every aggregation:
//     logit = Anorm@s + c2; s = Anorm@q + sb; q = Anorm@z + qb;
//     z = x@uu + zb0,  uu = W1@Wg0@Wg1@Wg2@W2  (a single 128-vector).
//   So gemm0 (~22us) and the 128-dim aggQ (59us, 191MB fetch) are GONE.
//   Remaining: CSR build + one dense matvec (reads x once = 51.2MB, the
//   mandatory-input floor) + three scalar gathers over the same CSR.
//   Scaling per hop (R18 pattern): vd stored pre-scaled by dinv;
//   v'_i = di*(sum_j w_ij vd_j + vd_i) + K; store v'_i*di for next hop.
// R18/R17: scatterRes (reservation sort, CAPB=2560, 1024thr) + countWrite
//   (bucket-local CSR, int2 rp). R16 calibration: ~150us fixed harness
//   overhead; dispatch boundaries ~free under graph replay.
// R14/R13: zero per-edge global atomics (returning u64 atomics execute
//   memory-side regardless of scope; 22G/s floor).
// Determinism: deg via fixed-point u32 adds; z/q/s/logit all fp32 (no bf16
//   re-quantization of order-dependent sums); bf16 only on edge weights
//   (deterministic per-edge quantization, as in R17/R18 -- passed at 0.0039).

#define CAPB  2560      // rec slots per bucket (u64)
#define EDCAP 3584      // edata words per bucket (2560 + 128*7 pad, rounded)

// ---------- bf16 helper ----------
__device__ __forceinline__ unsigned f2bf(float f) {      // RNE float->bf16 bits
    unsigned u = __float_as_uint(f);
    u += 0x7fffu + ((u >> 16) & 1u);
    return u >> 16;
}

// ---------- prep: uu = W1@Wg0@Wg1@Wg2@W2 chain + scalars + resCur init ----------
// kc = [zb0, qb, sb, c2] = [b1.u0, bg0.wv, bg1.wc2, bg2.W2 + b2]
__global__ __launch_bounds__(1024) void prep_kernel(const float* __restrict__ W1,
                                                    const float* __restrict__ b1,
                                                    const float* __restrict__ Wg,
                                                    const float* __restrict__ bg,
                                                    const float* __restrict__ W2,
                                                    const float* __restrict__ b2,
                                                    float* __restrict__ uu,
                                                    float* __restrict__ kc,
                                                    unsigned* __restrict__ resCur, int NB) {
    __shared__ float wc2[128], wv[128], u0[128];
    int t = threadIdx.x;
    if (t < NB) resCur[t] = (unsigned)t * CAPB;          // bucket reservation cursors
    if (t < 128) {                                       // wc2 = Wg2 @ W2
        float a = 0.f;
        for (int j = 0; j < 128; ++j) a += Wg[2 * 16384 + t * 128 + j] * W2[j];
        wc2[t] = a;
    }
    __syncthreads();
    if (t < 128) {                                       // wv = Wg1 @ wc2
        float a = 0.f;
        for (int j = 0; j < 128; ++j) a += Wg[16384 + t * 128 + j] * wc2[j];
        wv[t] = a;
    }
    __syncthreads();
    if (t < 128) {                                       // u0 = Wg0 @ wv
        float a = 0.f;
        for (int j = 0; j < 128; ++j) a += Wg[t * 128 + j] * wv[j];
        u0[t] = a;
    }
    __syncthreads();
    if (t < 128) {                                       // uu = W1 @ u0
        float a = 0.f;
        for (int j = 0; j < 128; ++j) a += W1[t * 128 + j] * u0[j];
        uu[t] = a;
    }
    if (t == 0) { float a = 0.f; for (int j = 0; j < 128; ++j) a += b1[j] * u0[j];        kc[0] = a; }
    if (t == 1) { float a = 0.f; for (int j = 0; j < 128; ++j) a += bg[j] * wv[j];        kc[1] = a; }
    if (t == 2) { float a = 0.f; for (int j = 0; j < 128; ++j) a += bg[128 + j] * wc2[j]; kc[2] = a; }
    if (t == 3) { float a = b2[0]; for (int j = 0; j < 128; ++j) a += bg[256 + j] * W2[j]; kc[3] = a; }
}

// ---------- scatterRes: LDS histogram -> global range reservation -> scatter ----------
// chunk = 8192 edges; 1024 threads (8 edges/thread); bucket = 128 dst nodes.
// rec[b*CAPB ..] = ((src<<7 | col&127) << 32) | f32bits(ew). ~153K global atomics.
__global__ __launch_bounds__(1024) void scatterRes_kernel(const int* __restrict__ row,
                                                          const int* __restrict__ col,
                                                          const float* __restrict__ ew,
                                                          unsigned* __restrict__ resCur,
                                                          unsigned long long* __restrict__ rec,
                                                          int E, int NB) {
    __shared__ unsigned cnt[1024];
    int b = blockIdx.x, t = threadIdx.x;
    cnt[t] = 0;
    __syncthreads();
    int base = b * 8192;
#pragma unroll
    for (int i = 0; i < 8; ++i) {
        int e = base + i * 1024 + t;
        if (e < E) atomicAdd(&cnt[(unsigned)col[e] >> 7], 1u);
    }
    __syncthreads();
    if (t < NB) {
        unsigned c = cnt[t];
        cnt[t] = c ? atomicAdd(&resCur[t], c) : 0u;   // reserve [base, base+c)
    }
    __syncthreads();
#pragma unroll
    for (int i = 0; i < 8; ++i) {
        int e = base + i * 1024 + t;
        if (e < E) {
            unsigned c = (unsigned)col[e];
            unsigned pos = atomicAdd(&cnt[c >> 7], 1u);          // LDS cursor
            rec[pos] = ((unsigned long long)(((unsigned)row[e] << 7) | (c & 127u)) << 32)
                     | (unsigned long long)__float_as_uint(ew[e]);
        }
    }
}

// ---------- countWrite: per-bucket counts + deg + rp + edata (src, bf16 w) ----------
// Bucket-local edata layout (bucket b owns words [b*EDCAP,(b+1)*EDCAP)); rp=(start,end).
__global__ __launch_bounds__(256) void countWrite_kernel(const unsigned long long* __restrict__ rec,
                                                         const unsigned* __restrict__ resCur,
                                                         float* __restrict__ dinv,
                                                         int2* __restrict__ rp,
                                                         unsigned* __restrict__ edata,
                                                         int n, int NB) {
    __shared__ unsigned lcnt[128];
    __shared__ unsigned ldeg[128];
    __shared__ unsigned lpre[128];
    __shared__ unsigned curp[128];
    int b = blockIdx.x, t = threadIdx.x;
    unsigned rbase = (unsigned)b * CAPB;
    unsigned tb = min(resCur[b] - rbase, (unsigned)CAPB);   // edges in this bucket
    if (t < 128) { lcnt[t] = 0; ldeg[t] = 0; }
    __syncthreads();
    for (unsigned i = t; i < tb; i += 256) {
        unsigned long long r = rec[rbase + i];
        unsigned cl = (unsigned)(r >> 32) & 127u;
        float w = __uint_as_float((unsigned)r);
        atomicAdd(&lcnt[cl], 1u);
        atomicAdd(&ldeg[cl], (unsigned)(w * 16777216.0f));  // same truncation as R12
    }
    __syncthreads();
    int node = b * 128 + t;
    unsigned c = 0, pv = 0;
    if (t < 128) {
        if (node < n) { c = lcnt[t]; pv = (c + 7) & ~7u; }
        lpre[t] = pv;
    }
    __syncthreads();
    for (int off = 1; off < 128; off <<= 1) {               // inclusive scan over 128
        unsigned u = (t < 128 && t >= off) ? lpre[t - off] : 0;
        __syncthreads();
        if (t < 128) lpre[t] += u;
        __syncthreads();
    }
    if (t < 128 && node < n) {
        unsigned st = (unsigned)b * EDCAP + lpre[t] - pv;   // bucket-local exclusive
        dinv[node] = rsqrtf(1.0f + (float)ldeg[t] * (1.0f / 16777216.0f));
        rp[node] = make_int2((int)st, (int)(st + pv));
        curp[t] = st;
        for (unsigned z = c; z < pv; ++z) edata[st + z] = 0;   // zero pad slots
    }
    __syncthreads();
    for (unsigned i = t; i < tb; i += 256) {
        unsigned long long r = rec[rbase + i];
        unsigned key = (unsigned)(r >> 32);
        unsigned cl = key & 127u, src = key >> 7;
        float w = __uint_as_float((unsigned)r);
        unsigned pos = atomicAdd(&curp[cl], 1u);            // LDS cursor
        edata[pos] = (src << 15) | (f2bf(w) & 0x7fffu);     // raw weight only
    }
}

// ---------- zd: z_i = x_i . uu + zb0; store zd = z*dinv (one 32-lane group/row) ----------
__global__ __launch_bounds__(256) void zd_kernel(const float* __restrict__ x,
                                                 const float* __restrict__ uu,
                                                 const float* __restrict__ kc,
                                                 const float* __restrict__ dinv,
                                                 float* __restrict__ zd, int n) {
    int wid = (int)((blockIdx.x * (size_t)blockDim.x + threadIdx.x) >> 5);
    int fl = threadIdx.x & 31;              // 32 lanes x float4 = 128 floats
    if (wid >= n) return;
    float4 xv = ((const float4*)(x + (size_t)wid * 128))[fl];
    float4 uv = ((const float4*)uu)[fl];
    float d = xv.x * uv.x + xv.y * uv.y + xv.z * uv.z + xv.w * uv.w;
#pragma unroll
    for (int off = 16; off > 0; off >>= 1) d += __shfl_xor(d, off);
    if (fl == 0) zd[wid] = (d + kc[0]) * dinv[wid];
}

// ---------- scalar aggregation: v_out = di*(acc + vals[i]) + K ----------
// vals pre-scaled by dinv. FINAL=0: write v_out*di (pre-scale for next hop).
// FINAL=1: write sigmoid(v_out).
template<int FINAL>
__global__ __launch_bounds__(256) void scalarAgg_kernel(const float* __restrict__ vals,
                                                        const int2* __restrict__ rp,
                                                        const unsigned* __restrict__ edata,
                                                        const float* __restrict__ dinv,
                                                        const float* __restrict__ kc,
                                                        float* __restrict__ out, int n) {
    int wid  = (int)((blockIdx.x * (size_t)blockDim.x + threadIdx.x) >> 6);
    int lane = threadIdx.x & 63;
    if (wid >= n) return;
    int2 seg = rp[wid];
    int start = seg.x, end = seg.y;
    float acc = 0.f;
    for (int base = start; base < end; base += 64) {
        int idx = base + lane;
        if (idx < end) {                      // pads have w=0 -> harmless
            unsigned ed = edata[idx];
            float w = __uint_as_float((ed & 0x7fffu) << 16);
            acc += w * vals[ed >> 15];
        }
    }
#pragma unroll
    for (int off = 32; off > 0; off >>= 1) acc += __shfl_xor(acc, off);
    if (lane == 0) {
        float di = dinv[wid];
        float d = di * (acc + vals[wid]) + kc[0];
        out[wid] = FINAL ? 1.0f / (1.0f + expf(-d)) : d * di;
    }
}

static inline char* align16(char* p) { return (char*)(((uintptr_t)p + 15) & ~(uintptr_t)15); }

extern "C" void kernel_launch(void* const* d_in, const int* in_sizes, int n_in,
                              void* d_out, int out_size, void* d_ws, size_t ws_size,
                              hipStream_t stream) {
    const float* x  = (const float*)d_in[0];
    const int*   ei = (const int*)d_in[1];   // [2, E] int32
    const float* ea = (const float*)d_in[2]; // [E]
    const float* W1 = (const float*)d_in[3];
    const float* b1 = (const float*)d_in[4];
    const float* Wg = (const float*)d_in[5]; // [3,128,128]
    const float* bg = (const float*)d_in[6]; // [3,128]
    const float* W2 = (const float*)d_in[7]; // [128]
    const float* b2 = (const float*)d_in[8]; // [1]

    const int N = in_sizes[0] / 128;
    const int E = in_sizes[2];
    const int* row = ei;
    const int* col = ei + E;

    const int NB = (N + 127) >> 7;           // buckets of 128 nodes (782)
    const int NC = (E + 8191) >> 13;         // 8192-edge chunks (196)

    // workspace layout
    char* p = (char*)d_ws;
    unsigned long long* rec = (unsigned long long*)p; p += (size_t)NB * CAPB * 8; // 16MB
    float* uu  = (float*)p;  p += 128 * 4;
    float* kc  = (float*)p;  p += 16;
    float* zdv = (float*)p;  p += (size_t)N * 4;
    float* qdv = (float*)p;  p += (size_t)N * 4;
    float* sdv = (float*)p;  p += (size_t)N * 4;
    p = align16(p);
    unsigned* resCur = (unsigned*)p; p += (size_t)NB * 4; p = align16(p);
    float* dinv = (float*)p; p += (size_t)N * 4;
    int2* rp    = (int2*)p;  p += (size_t)N * 8; p = align16(p);
    unsigned* edata = (unsigned*)p;            // NB*EDCAP words (~11.2MB)

    dim3 b256(256);
    int wave_blocks = (int)(((size_t)N * 64 + 255) / 256);   // 1 wave / node
    int half_blocks = (int)(((size_t)N * 32 + 255) / 256);   // 1 half-wave / node

    // D1: weight-chain collapse (uu, kc) + reservation cursors
    prep_kernel<<<1, dim3(1024), 0, stream>>>(W1, b1, Wg, bg, W2, b2, uu, kc, resCur, NB);
    // D2: bucket-sort edges into rec
    scatterRes_kernel<<<NC, dim3(1024), 0, stream>>>(row, col, ea, resCur, rec, E, NB);
    // D3: per-bucket counts + deg/dinv + rp + edata(src, bf16 w)
    countWrite_kernel<<<NB, b256, 0, stream>>>(rec, resCur, dinv, rp, edata, N, NB);
    // D4: zd = (x . uu + zb0) * dinv   (reads x once -- the input floor)
    zd_kernel<<<half_blocks, b256, 0, stream>>>(x, uu, kc, dinv, zdv, N);
    // D5-D7: three scalar hops  q -> s -> logit/sigmoid
    scalarAgg_kernel<0><<<wave_blocks, b256, 0, stream>>>(zdv, rp, edata, dinv, kc + 1, qdv, N);
    scalarAgg_kernel<0><<<wave_blocks, b256, 0, stream>>>(qdv, rp, edata, dinv, kc + 2, sdv, N);
    scalarAgg_kernel<1><<<wave_blocks, b256, 0, stream>>>(sdv, rp, edata, dinv, kc + 3,
                                                          (float*)d_out, N);
}

// Round 8
// 203.820 us; speedup vs baseline: 6.9664x; 1.0926x over previous
//
#include <hip/hip_runtime.h>
#include <cstdint>
#include <cstddef>

// SimpleGCN: h = x@W1+b1; 3x GCNConv(sym-norm adj w/ self loops); sigmoid(h@W2+b2)
// N=100000, d=128, E=1.6M.
// R20 = R19 + lane-utilization + overlap:
//   - scalarAgg: 8 lanes/node (pads are multiples of 8 -> full groups, no
//     divergence; 3-step shfl_xor). R19 used 64 lanes/node at deg~16 -> ~70%
//     idle. 8x fewer waves per hop.
//   - fused2: scatterRes (blocks [0,NC)) || zd (rest) in ONE dispatch; zd
//     writes UNSCALED z; countWrite applies dinv (it owns each node's dinv).
//   - R19 profile: top-5 = harness's 256MB ws fill (41us, fixed) -> all our
//     kernels < 40us; controllable ~70us.
// R19: total linear collapse: logit = A@(A@(A@z+qb)+sb)+c2, z = x.uu+zb0,
//   uu = W1@Wg0@Wg1@Wg2@W2. No GEMM, no 128-dim gather; x read once (51MB).
// R18/R17: scatterRes (reservation sort, CAPB=2560, 1024thr) + countWrite
//   (bucket-local CSR, int2 rp). R16: ~150us fixed harness overhead/iter.
// R14/R13: zero per-edge global atomics (returning u64 atomics execute
//   memory-side regardless of scope; 22G/s floor).
// Determinism: deg via fixed-point u32 adds; z/q/s/logit all fp32; bf16 only
//   on edge weights (deterministic per-edge quantization; passed at 0.0039).

#define CAPB  2560      // rec slots per bucket (u64)
#define EDCAP 3584      // edata words per bucket (2560 + 128*7 pad, mult of 8)

// ---------- bf16 helper ----------
__device__ __forceinline__ unsigned f2bf(float f) {      // RNE float->bf16 bits
    unsigned u = __float_as_uint(f);
    u += 0x7fffu + ((u >> 16) & 1u);
    return u >> 16;
}

// ---------- prep: uu = W1@Wg0@Wg1@Wg2@W2 chain + scalars + resCur init ----------
// kc = [zb0, qb, sb, c2] = [b1.u0, bg0.wv, bg1.wc2, bg2.W2 + b2]
__global__ __launch_bounds__(1024) void prep_kernel(const float* __restrict__ W1,
                                                    const float* __restrict__ b1,
                                                    const float* __restrict__ Wg,
                                                    const float* __restrict__ bg,
                                                    const float* __restrict__ W2,
                                                    const float* __restrict__ b2,
                                                    float* __restrict__ uu,
                                                    float* __restrict__ kc,
                                                    unsigned* __restrict__ resCur, int NB) {
    __shared__ float wc2[128], wv[128], u0[128];
    int t = threadIdx.x;
    if (t < NB) resCur[t] = (unsigned)t * CAPB;          // bucket reservation cursors
    if (t < 128) {                                       // wc2 = Wg2 @ W2
        float a = 0.f;
        for (int j = 0; j < 128; ++j) a += Wg[2 * 16384 + t * 128 + j] * W2[j];
        wc2[t] = a;
    }
    __syncthreads();
    if (t < 128) {                                       // wv = Wg1 @ wc2
        float a = 0.f;
        for (int j = 0; j < 128; ++j) a += Wg[16384 + t * 128 + j] * wc2[j];
        wv[t] = a;
    }
    __syncthreads();
    if (t < 128) {                                       // u0 = Wg0 @ wv
        float a = 0.f;
        for (int j = 0; j < 128; ++j) a += Wg[t * 128 + j] * wv[j];
        u0[t] = a;
    }
    __syncthreads();
    if (t < 128) {                                       // uu = W1 @ u0
        float a = 0.f;
        for (int j = 0; j < 128; ++j) a += W1[t * 128 + j] * u0[j];
        uu[t] = a;
    }
    if (t == 0) { float a = 0.f; for (int j = 0; j < 128; ++j) a += b1[j] * u0[j];        kc[0] = a; }
    if (t == 1) { float a = 0.f; for (int j = 0; j < 128; ++j) a += bg[j] * wv[j];        kc[1] = a; }
    if (t == 2) { float a = 0.f; for (int j = 0; j < 128; ++j) a += bg[128 + j] * wc2[j]; kc[2] = a; }
    if (t == 3) { float a = b2[0]; for (int j = 0; j < 128; ++j) a += bg[256 + j] * W2[j]; kc[3] = a; }
}

// ---------- fused2: scatterRes (blocks [0,NC)) || zd unscaled (blocks [NC,..)) ----------
// scatterRes: chunk = 8192 edges; 1024 threads; bucket = 128 dst nodes;
//   rec[b*CAPB ..] = ((src<<7 | col&127) << 32) | f32bits(ew). ~153K global atomics.
// zd: 32 lanes/row; z_i = x_i . uu + zb0 (UNSCALED; countWrite applies dinv).
__global__ __launch_bounds__(1024) void fused2_kernel(const int* __restrict__ row,
                                                      const int* __restrict__ col,
                                                      const float* __restrict__ ew,
                                                      unsigned* __restrict__ resCur,
                                                      unsigned long long* __restrict__ rec,
                                                      const float* __restrict__ x,
                                                      const float* __restrict__ uu,
                                                      const float* __restrict__ kc,
                                                      float* __restrict__ zdv,
                                                      int E, int NB, int NC, int n) {
    __shared__ unsigned cnt[1024];
    int b = blockIdx.x, t = threadIdx.x;
    if (b < NC) {
        cnt[t] = 0;
        __syncthreads();
        int base = b * 8192;
#pragma unroll
        for (int i = 0; i < 8; ++i) {
            int e = base + i * 1024 + t;
            if (e < E) atomicAdd(&cnt[(unsigned)col[e] >> 7], 1u);
        }
        __syncthreads();
        if (t < NB) {
            unsigned c = cnt[t];
            cnt[t] = c ? atomicAdd(&resCur[t], c) : 0u;   // reserve [base, base+c)
        }
        __syncthreads();
#pragma unroll
        for (int i = 0; i < 8; ++i) {
            int e = base + i * 1024 + t;
            if (e < E) {
                unsigned c = (unsigned)col[e];
                unsigned pos = atomicAdd(&cnt[c >> 7], 1u);          // LDS cursor
                rec[pos] = ((unsigned long long)(((unsigned)row[e] << 7) | (c & 127u)) << 32)
                         | (unsigned long long)__float_as_uint(ew[e]);
            }
        }
    } else {
        int r = (b - NC) * 32 + (t >> 5);
        int fl = t & 31;                    // 32 lanes x float4 = 128 floats
        if (r < n) {
            float4 xv = ((const float4*)(x + (size_t)r * 128))[fl];
            float4 uv = ((const float4*)uu)[fl];
            float d = xv.x * uv.x + xv.y * uv.y + xv.z * uv.z + xv.w * uv.w;
#pragma unroll
            for (int off = 16; off > 0; off >>= 1) d += __shfl_xor(d, off);
            if (fl == 0) zdv[r] = d + kc[0];            // unscaled z
        }
    }
}

// ---------- countWrite: counts + deg + rp + edata (src, bf16 w) + z scaling ----------
// Bucket-local edata layout (bucket b owns words [b*EDCAP,(b+1)*EDCAP)); rp=(start,end).
__global__ __launch_bounds__(256) void countWrite_kernel(const unsigned long long* __restrict__ rec,
                                                         const unsigned* __restrict__ resCur,
                                                         float* __restrict__ dinv,
                                                         int2* __restrict__ rp,
                                                         unsigned* __restrict__ edata,
                                                         float* __restrict__ zdv,
                                                         int n, int NB) {
    __shared__ unsigned lcnt[128];
    __shared__ unsigned ldeg[128];
    __shared__ unsigned lpre[128];
    __shared__ unsigned curp[128];
    int b = blockIdx.x, t = threadIdx.x;
    unsigned rbase = (unsigned)b * CAPB;
    unsigned tb = min(resCur[b] - rbase, (unsigned)CAPB);   // edges in this bucket
    if (t < 128) { lcnt[t] = 0; ldeg[t] = 0; }
    __syncthreads();
    for (unsigned i = t; i < tb; i += 256) {
        unsigned long long r = rec[rbase + i];
        unsigned cl = (unsigned)(r >> 32) & 127u;
        float w = __uint_as_float((unsigned)r);
        atomicAdd(&lcnt[cl], 1u);
        atomicAdd(&ldeg[cl], (unsigned)(w * 16777216.0f));  // same truncation as R12
    }
    __syncthreads();
    int node = b * 128 + t;
    unsigned c = 0, pv = 0;
    if (t < 128) {
        if (node < n) { c = lcnt[t]; pv = (c + 7) & ~7u; }
        lpre[t] = pv;
    }
    __syncthreads();
    for (int off = 1; off < 128; off <<= 1) {               // inclusive scan over 128
        unsigned u = (t < 128 && t >= off) ? lpre[t - off] : 0;
        __syncthreads();
        if (t < 128) lpre[t] += u;
        __syncthreads();
    }
    if (t < 128 && node < n) {
        unsigned st = (unsigned)b * EDCAP + lpre[t] - pv;   // bucket-local exclusive
        float di = rsqrtf(1.0f + (float)ldeg[t] * (1.0f / 16777216.0f));
        dinv[node] = di;
        zdv[node] *= di;                                    // scale z (was unscaled)
        rp[node] = make_int2((int)st, (int)(st + pv));
        curp[t] = st;
        for (unsigned z = c; z < pv; ++z) edata[st + z] = 0;   // zero pad slots
    }
    __syncthreads();
    for (unsigned i = t; i < tb; i += 256) {
        unsigned long long r = rec[rbase + i];
        unsigned key = (unsigned)(r >> 32);
        unsigned cl = key & 127u, src = key >> 7;
        float w = __uint_as_float((unsigned)r);
        unsigned pos = atomicAdd(&curp[cl], 1u);            // LDS cursor
        edata[pos] = (src << 15) | (f2bf(w) & 0x7fffu);     // raw weight only
    }
}

// ---------- scalar aggregation, 8 lanes/node: v_out = di*(acc + vals[i]) + K ----------
// vals pre-scaled by dinv; segments padded to mult of 8 -> full 8-lane groups,
// no divergence (pads have w=0). FINAL=0: write v_out*di. FINAL=1: sigmoid.
template<int FINAL>
__global__ __launch_bounds__(256) void scalarAgg_kernel(const float* __restrict__ vals,
                                                        const int2* __restrict__ rp,
                                                        const unsigned* __restrict__ edata,
                                                        const float* __restrict__ dinv,
                                                        const float* __restrict__ kc,
                                                        float* __restrict__ out, int n) {
    int gid  = blockIdx.x * 256 + threadIdx.x;
    int wid  = gid >> 3;
    int l8   = gid & 7;
    if (wid >= n) return;
    int2 seg = rp[wid];
    float acc = 0.f;
    for (int idx = seg.x + l8; idx < seg.y; idx += 8) {
        unsigned ed = edata[idx];             // pads: w=0, src=0 -> harmless
        float w = __uint_as_float((ed & 0x7fffu) << 16);
        acc += w * vals[ed >> 15];
    }
#pragma unroll
    for (int off = 4; off > 0; off >>= 1) acc += __shfl_xor(acc, off);
    if (l8 == 0) {
        float di = dinv[wid];
        float d = di * (acc + vals[wid]) + kc[0];
        out[wid] = FINAL ? 1.0f / (1.0f + expf(-d)) : d * di;
    }
}

static inline char* align16(char* p) { return (char*)(((uintptr_t)p + 15) & ~(uintptr_t)15); }

extern "C" void kernel_launch(void* const* d_in, const int* in_sizes, int n_in,
                              void* d_out, int out_size, void* d_ws, size_t ws_size,
                              hipStream_t stream) {
    const float* x  = (const float*)d_in[0];
    const int*   ei = (const int*)d_in[1];   // [2, E] int32
    const float* ea = (const float*)d_in[2]; // [E]
    const float* W1 = (const float*)d_in[3];
    const float* b1 = (const float*)d_in[4];
    const float* Wg = (const float*)d_in[5]; // [3,128,128]
    const float* bg = (const float*)d_in[6]; // [3,128]
    const float* W2 = (const float*)d_in[7]; // [128]
    const float* b2 = (const float*)d_in[8]; // [1]

    const int N = in_sizes[0] / 128;
    const int E = in_sizes[2];
    const int* row = ei;
    const int* col = ei + E;

    const int NB = (N + 127) >> 7;           // buckets of 128 nodes (782)
    const int NC = (E + 8191) >> 13;         // 8192-edge chunks (196)
    const int NZ = (N + 31) >> 5;            // zd blocks (32 rows each @1024thr)

    // workspace layout
    char* p = (char*)d_ws;
    unsigned long long* rec = (unsigned long long*)p; p += (size_t)NB * CAPB * 8; // 16MB
    float* uu  = (float*)p;  p += 128 * 4;
    float* kc  = (float*)p;  p += 16;
    float* zdv = (float*)p;  p += (size_t)N * 4;
    float* qdv = (float*)p;  p += (size_t)N * 4;
    float* sdv = (float*)p;  p += (size_t)N * 4;
    p = align16(p);
    unsigned* resCur = (unsigned*)p; p += (size_t)NB * 4; p = align16(p);
    float* dinv = (float*)p; p += (size_t)N * 4;
    int2* rp    = (int2*)p;  p += (size_t)N * 8; p = align16(p);
    unsigned* edata = (unsigned*)p;            // NB*EDCAP words (~11.2MB)

    dim3 b256(256);
    int agg_blocks = (int)(((size_t)N * 8 + 255) / 256);   // 8 lanes / node

    // D1: weight-chain collapse (uu, kc) + reservation cursors
    prep_kernel<<<1, dim3(1024), 0, stream>>>(W1, b1, Wg, bg, W2, b2, uu, kc, resCur, NB);
    // D2: scatterRes || zd (independent; zd writes unscaled z)
    fused2_kernel<<<NC + NZ, dim3(1024), 0, stream>>>(row, col, ea, resCur, rec,
                                                      x, uu, kc, zdv, E, NB, NC, N);
    // D3: per-bucket counts + deg/dinv + rp + edata(src, bf16 w) + z scaling
    countWrite_kernel<<<NB, b256, 0, stream>>>(rec, resCur, dinv, rp, edata, zdv, N, NB);
    // D4-D6: three scalar hops  q -> s -> logit/sigmoid (8 lanes/node)
    scalarAgg_kernel<0><<<agg_blocks, b256, 0, stream>>>(zdv, rp, edata, dinv, kc + 1, qdv, N);
    scalarAgg_kernel<0><<<agg_blocks, b256, 0, stream>>>(qdv, rp, edata, dinv, kc + 2, sdv, N);
    scalarAgg_kernel<1><<<agg_blocks, b256, 0, stream>>>(sdv, rp, edata, dinv, kc + 3,
                                                         (float*)d_out, N);
}

// Round 9
// 186.468 us; speedup vs baseline: 7.6146x; 1.0931x over previous
//
#include <hip/hip_runtime.h>
#include <cstdint>
#include <cstddef>

// SimpleGCN: h = x@W1+b1; 3x GCNConv(sym-norm adj w/ self loops); sigmoid(h@W2+b2)
// N=100000, d=128, E=1.6M.
// R21 = R20 + fused2 latency fix (R20 profile: fused2 43us at VALU 8.8%,
//   HBM 22%, occ 57% -> latency-bound; only custom kernel left in top-5,
//   everything else is the harness's fixed 256MB ws fill ~150us/iter):
//   - register-resident edges: 8 contiguous edges/thread loaded ONCE as
//     int4x2(col)+int4x2(row)+float4x2(ew) -> 6 coalesced wide loads in
//     flight; histogram + scatter both run from regs (col read once).
//   - full-chunk specialization: 195/196 chunks have no per-edge guards.
//   - countWrite reads rec as ulonglong2 (16B/lane).
// R20: 8-lane scalarAgg hops; scatterRes||zd fused; countWrite scales z.
// R19: total linear collapse: logit = A@(A@(A@z+qb)+sb)+c2, z = x.uu+zb0,
//   uu = W1@Wg0@Wg1@Wg2@W2. No GEMM, no 128-dim gather; x read once.
// R18/R17: reservation sort (CAPB=2560) + bucket-local CSR (int2 rp).
// R16: ~150us fixed harness overhead/iter; dispatch boundaries ~free.
// R14/R13: zero per-edge global atomics (returning u64 atomics execute
//   memory-side regardless of scope; 22G/s floor).
// Determinism: deg via fixed-point u32 adds; z/q/s/logit all fp32; bf16 only
//   on edge weights (deterministic per-edge quantization; passed at 0.0039).

#define CAPB  2560      // rec slots per bucket (u64)
#define EDCAP 3584      // edata words per bucket (2560 + 128*7 pad, mult of 8)

// ---------- bf16 helper ----------
__device__ __forceinline__ unsigned f2bf(float f) {      // RNE float->bf16 bits
    unsigned u = __float_as_uint(f);
    u += 0x7fffu + ((u >> 16) & 1u);
    return u >> 16;
}

// ---------- prep: uu = W1@Wg0@Wg1@Wg2@W2 chain + scalars + resCur init ----------
// kc = [zb0, qb, sb, c2] = [b1.u0, bg0.wv, bg1.wc2, bg2.W2 + b2]
__global__ __launch_bounds__(1024) void prep_kernel(const float* __restrict__ W1,
                                                    const float* __restrict__ b1,
                                                    const float* __restrict__ Wg,
                                                    const float* __restrict__ bg,
                                                    const float* __restrict__ W2,
                                                    const float* __restrict__ b2,
                                                    float* __restrict__ uu,
                                                    float* __restrict__ kc,
                                                    unsigned* __restrict__ resCur, int NB) {
    __shared__ float wc2[128], wv[128], u0[128];
    int t = threadIdx.x;
    if (t < NB) resCur[t] = (unsigned)t * CAPB;          // bucket reservation cursors
    if (t < 128) {                                       // wc2 = Wg2 @ W2
        float a = 0.f;
        for (int j = 0; j < 128; ++j) a += Wg[2 * 16384 + t * 128 + j] * W2[j];
        wc2[t] = a;
    }
    __syncthreads();
    if (t < 128) {                                       // wv = Wg1 @ wc2
        float a = 0.f;
        for (int j = 0; j < 128; ++j) a += Wg[16384 + t * 128 + j] * wc2[j];
        wv[t] = a;
    }
    __syncthreads();
    if (t < 128) {                                       // u0 = Wg0 @ wv
        float a = 0.f;
        for (int j = 0; j < 128; ++j) a += Wg[t * 128 + j] * wv[j];
        u0[t] = a;
    }
    __syncthreads();
    if (t < 128) {                                       // uu = W1 @ u0
        float a = 0.f;
        for (int j = 0; j < 128; ++j) a += W1[t * 128 + j] * u0[j];
        uu[t] = a;
    }
    if (t == 0) { float a = 0.f; for (int j = 0; j < 128; ++j) a += b1[j] * u0[j];        kc[0] = a; }
    if (t == 1) { float a = 0.f; for (int j = 0; j < 128; ++j) a += bg[j] * wv[j];        kc[1] = a; }
    if (t == 2) { float a = 0.f; for (int j = 0; j < 128; ++j) a += bg[128 + j] * wc2[j]; kc[2] = a; }
    if (t == 3) { float a = b2[0]; for (int j = 0; j < 128; ++j) a += bg[256 + j] * W2[j]; kc[3] = a; }
}

// ---------- fused2: scatterRes (blocks [0,NC)) || zd unscaled (blocks [NC,..)) ----------
// scatterRes: chunk = 8192 edges; 1024 threads; 8 CONTIGUOUS edges/thread held
//   in registers (int4x2 col, int4x2 row, float4x2 ew loaded once, coalesced);
//   bucket = 128 dst nodes; rec = ((src<<7 | col&127) << 32) | f32bits(ew).
//   Full chunks (all but last) run guard-free.
// zd: 32 lanes/row; z_i = x_i . uu + zb0 (UNSCALED; countWrite applies dinv).
__global__ __launch_bounds__(1024) void fused2_kernel(const int* __restrict__ row,
                                                      const int* __restrict__ col,
                                                      const float* __restrict__ ew,
                                                      unsigned* __restrict__ resCur,
                                                      unsigned long long* __restrict__ rec,
                                                      const float* __restrict__ x,
                                                      const float* __restrict__ uu,
                                                      const float* __restrict__ kc,
                                                      float* __restrict__ zdv,
                                                      int E, int NB, int NC, int n) {
    __shared__ unsigned cnt[1024];
    int b = blockIdx.x, t = threadIdx.x;
    if (b < NC) {
        cnt[t] = 0;
        __syncthreads();
        int base = b * 8192;
        if (base + 8192 <= E) {
            // ---- fast path: full chunk, register-resident, no guards ----
            int e0 = base + t * 8;
            int4   c0 = ((const int4*)(col + e0))[0];
            int4   c1 = ((const int4*)(col + e0))[1];
            int4   r0 = ((const int4*)(row + e0))[0];
            int4   r1 = ((const int4*)(row + e0))[1];
            float4 w0 = ((const float4*)(ew + e0))[0];
            float4 w1 = ((const float4*)(ew + e0))[1];
            int   c[8] = {c0.x, c0.y, c0.z, c0.w, c1.x, c1.y, c1.z, c1.w};
            int   r[8] = {r0.x, r0.y, r0.z, r0.w, r1.x, r1.y, r1.z, r1.w};
            float w[8] = {w0.x, w0.y, w0.z, w0.w, w1.x, w1.y, w1.z, w1.w};
#pragma unroll
            for (int i = 0; i < 8; ++i)
                atomicAdd(&cnt[(unsigned)c[i] >> 7], 1u);
            __syncthreads();
            if (t < NB) {
                unsigned cc = cnt[t];
                cnt[t] = cc ? atomicAdd(&resCur[t], cc) : 0u;   // reserve range
            }
            __syncthreads();
#pragma unroll
            for (int i = 0; i < 8; ++i) {
                unsigned cc = (unsigned)c[i];
                unsigned pos = atomicAdd(&cnt[cc >> 7], 1u);    // LDS cursor
                rec[pos] = ((unsigned long long)(((unsigned)r[i] << 7) | (cc & 127u)) << 32)
                         | (unsigned long long)__float_as_uint(w[i]);
            }
        } else {
            // ---- tail chunk: guarded scalar path ----
            for (int i = 0; i < 8; ++i) {
                int e = base + i * 1024 + t;
                if (e < E) atomicAdd(&cnt[(unsigned)col[e] >> 7], 1u);
            }
            __syncthreads();
            if (t < NB) {
                unsigned cc = cnt[t];
                cnt[t] = cc ? atomicAdd(&resCur[t], cc) : 0u;
            }
            __syncthreads();
            for (int i = 0; i < 8; ++i) {
                int e = base + i * 1024 + t;
                if (e < E) {
                    unsigned cc = (unsigned)col[e];
                    unsigned pos = atomicAdd(&cnt[cc >> 7], 1u);
                    rec[pos] = ((unsigned long long)(((unsigned)row[e] << 7) | (cc & 127u)) << 32)
                             | (unsigned long long)__float_as_uint(ew[e]);
                }
            }
        }
    } else {
        int r = (b - NC) * 32 + (t >> 5);
        int fl = t & 31;                    // 32 lanes x float4 = 128 floats
        if (r < n) {
            float4 xv = ((const float4*)(x + (size_t)r * 128))[fl];
            float4 uv = ((const float4*)uu)[fl];
            float d = xv.x * uv.x + xv.y * uv.y + xv.z * uv.z + xv.w * uv.w;
#pragma unroll
            for (int off = 16; off > 0; off >>= 1) d += __shfl_xor(d, off);
            if (fl == 0) zdv[r] = d + kc[0];            // unscaled z
        }
    }
}

// ---------- countWrite: counts + deg + rp + edata (src, bf16 w) + z scaling ----------
// Bucket-local edata layout (bucket b owns words [b*EDCAP,(b+1)*EDCAP)); rp=(start,end).
__global__ __launch_bounds__(256) void countWrite_kernel(const unsigned long long* __restrict__ rec,
                                                         const unsigned* __restrict__ resCur,
                                                         float* __restrict__ dinv,
                                                         int2* __restrict__ rp,
                                                         unsigned* __restrict__ edata,
                                                         float* __restrict__ zdv,
                                                         int n, int NB) {
    __shared__ unsigned lcnt[128];
    __shared__ unsigned ldeg[128];
    __shared__ unsigned lpre[128];
    __shared__ unsigned curp[128];
    int b = blockIdx.x, t = threadIdx.x;
    unsigned rbase = (unsigned)b * CAPB;
    unsigned tb = min(resCur[b] - rbase, (unsigned)CAPB);   // edges in this bucket
    if (t < 128) { lcnt[t] = 0; ldeg[t] = 0; }
    __syncthreads();
    // 2 edges/thread/iter (16B loads)
    for (unsigned i = t * 2; i < tb; i += 512) {
        unsigned long long r0 = rec[rbase + i];
        unsigned cl0 = (unsigned)(r0 >> 32) & 127u;
        float wv0 = __uint_as_float((unsigned)r0);
        atomicAdd(&lcnt[cl0], 1u);
        atomicAdd(&ldeg[cl0], (unsigned)(wv0 * 16777216.0f));   // same truncation as R12
        if (i + 1 < tb) {
            unsigned long long r1 = rec[rbase + i + 1];
            unsigned cl1 = (unsigned)(r1 >> 32) & 127u;
            float wv1 = __uint_as_float((unsigned)r1);
            atomicAdd(&lcnt[cl1], 1u);
            atomicAdd(&ldeg[cl1], (unsigned)(wv1 * 16777216.0f));
        }
    }
    __syncthreads();
    int node = b * 128 + t;
    unsigned c = 0, pv = 0;
    if (t < 128) {
        if (node < n) { c = lcnt[t]; pv = (c + 7) & ~7u; }
        lpre[t] = pv;
    }
    __syncthreads();
    for (int off = 1; off < 128; off <<= 1) {               // inclusive scan over 128
        unsigned u = (t < 128 && t >= off) ? lpre[t - off] : 0;
        __syncthreads();
        if (t < 128) lpre[t] += u;
        __syncthreads();
    }
    if (t < 128 && node < n) {
        unsigned st = (unsigned)b * EDCAP + lpre[t] - pv;   // bucket-local exclusive
        float di = rsqrtf(1.0f + (float)ldeg[t] * (1.0f / 16777216.0f));
        dinv[node] = di;
        zdv[node] *= di;                                    // scale z (was unscaled)
        rp[node] = make_int2((int)st, (int)(st + pv));
        curp[t] = st;
        for (unsigned z = c; z < pv; ++z) edata[st + z] = 0;   // zero pad slots
    }
    __syncthreads();
    for (unsigned i = t; i < tb; i += 256) {
        unsigned long long r = rec[rbase + i];
        unsigned key = (unsigned)(r >> 32);
        unsigned cl = key & 127u, src = key >> 7;
        float w = __uint_as_float((unsigned)r);
        unsigned pos = atomicAdd(&curp[cl], 1u);            // LDS cursor
        edata[pos] = (src << 15) | (f2bf(w) & 0x7fffu);     // raw weight only
    }
}

// ---------- scalar aggregation, 8 lanes/node: v_out = di*(acc + vals[i]) + K ----------
// vals pre-scaled by dinv; segments padded to mult of 8 -> full 8-lane groups,
// no divergence (pads have w=0). FINAL=0: write v_out*di. FINAL=1: sigmoid.
template<int FINAL>
__global__ __launch_bounds__(256) void scalarAgg_kernel(const float* __restrict__ vals,
                                                        const int2* __restrict__ rp,
                                                        const unsigned* __restrict__ edata,
                                                        const float* __restrict__ dinv,
                                                        const float* __restrict__ kc,
                                                        float* __restrict__ out, int n) {
    int gid  = blockIdx.x * 256 + threadIdx.x;
    int wid  = gid >> 3;
    int l8   = gid & 7;
    if (wid >= n) return;
    int2 seg = rp[wid];
    float acc = 0.f;
    for (int idx = seg.x + l8; idx < seg.y; idx += 8) {
        unsigned ed = edata[idx];             // pads: w=0, src=0 -> harmless
        float w = __uint_as_float((ed & 0x7fffu) << 16);
        acc += w * vals[ed >> 15];
    }
#pragma unroll
    for (int off = 4; off > 0; off >>= 1) acc += __shfl_xor(acc, off);
    if (l8 == 0) {
        float di = dinv[wid];
        float d = di * (acc + vals[wid]) + kc[0];
        out[wid] = FINAL ? 1.0f / (1.0f + expf(-d)) : d * di;
    }
}

static inline char* align16(char* p) { return (char*)(((uintptr_t)p + 15) & ~(uintptr_t)15); }

extern "C" void kernel_launch(void* const* d_in, const int* in_sizes, int n_in,
                              void* d_out, int out_size, void* d_ws, size_t ws_size,
                              hipStream_t stream) {
    const float* x  = (const float*)d_in[0];
    const int*   ei = (const int*)d_in[1];   // [2, E] int32
    const float* ea = (const float*)d_in[2]; // [E]
    const float* W1 = (const float*)d_in[3];
    const float* b1 = (const float*)d_in[4];
    const float* Wg = (const float*)d_in[5]; // [3,128,128]
    const float* bg = (const float*)d_in[6]; // [3,128]
    const float* W2 = (const float*)d_in[7]; // [128]
    const float* b2 = (const float*)d_in[8]; // [1]

    const int N = in_sizes[0] / 128;
    const int E = in_sizes[2];
    const int* row = ei;
    const int* col = ei + E;

    const int NB = (N + 127) >> 7;           // buckets of 128 nodes (782)
    const int NC = (E + 8191) >> 13;         // 8192-edge chunks (196)
    const int NZ = (N + 31) >> 5;            // zd blocks (32 rows each @1024thr)

    // workspace layout
    char* p = (char*)d_ws;
    unsigned long long* rec = (unsigned long long*)p; p += (size_t)NB * CAPB * 8; // 16MB
    float* uu  = (float*)p;  p += 128 * 4;
    float* kc  = (float*)p;  p += 16;
    float* zdv = (float*)p;  p += (size_t)N * 4;
    float* qdv = (float*)p;  p += (size_t)N * 4;
    float* sdv = (float*)p;  p += (size_t)N * 4;
    p = align16(p);
    unsigned* resCur = (unsigned*)p; p += (size_t)NB * 4; p = align16(p);
    float* dinv = (float*)p; p += (size_t)N * 4;
    int2* rp    = (int2*)p;  p += (size_t)N * 8; p = align16(p);
    unsigned* edata = (unsigned*)p;            // NB*EDCAP words (~11.2MB)

    dim3 b256(256);
    int agg_blocks = (int)(((size_t)N * 8 + 255) / 256);   // 8 lanes / node

    // D1: weight-chain collapse (uu, kc) + reservation cursors
    prep_kernel<<<1, dim3(1024), 0, stream>>>(W1, b1, Wg, bg, W2, b2, uu, kc, resCur, NB);
    // D2: scatterRes || zd (independent; zd writes unscaled z)
    fused2_kernel<<<NC + NZ, dim3(1024), 0, stream>>>(row, col, ea, resCur, rec,
                                                      x, uu, kc, zdv, E, NB, NC, N);
    // D3: per-bucket counts + deg/dinv + rp + edata(src, bf16 w) + z scaling
    countWrite_kernel<<<NB, b256, 0, stream>>>(rec, resCur, dinv, rp, edata, zdv, N, NB);
    // D4-D6: three scalar hops  q -> s -> logit/sigmoid (8 lanes/node)
    scalarAgg_kernel<0><<<agg_blocks, b256, 0, stream>>>(zdv, rp, edata, dinv, kc + 1, qdv, N);
    scalarAgg_kernel<0><<<agg_blocks, b256, 0, stream>>>(qdv, rp, edata, dinv, kc + 2, sdv, N);
    scalarAgg_kernel<1><<<agg_blocks, b256, 0, stream>>>(sdv, rp, edata, dinv, kc + 3,
                                                         (float*)d_out, N);
}

// Round 10
// 177.111 us; speedup vs baseline: 8.0169x; 1.0528x over previous
//
#include <hip/hip_runtime.h>
#include <cstdint>
#include <cstddef>

// SimpleGCN: h = x@W1+b1; 3x GCNConv(sym-norm adj w/ self loops); sigmoid(h@W2+b2)
// N=100000, d=128, E=1.6M.
// R22 = R21 + LDS-staged scatter + parallel prep.
//   R21 profile: all custom kernels below the harness's 256MB ws-fill (41us);
//   controllable ~36us. R20 counters: fused2 WRITE_SIZE 40.7MB vs 13.2 ideal
//   (3x amplification: 8B scattered rec writes -> partial-line evictions).
//   - fused2 scatter: chunk 4096 edges, 1024 thr; histogram -> EARLY global
//     range reservation (hidden under scan) -> 1024-entry exclusive scan ->
//     scatter into LDS srec[4096] with final global index sga[4096] ->
//     streaming LDS->global copy (runs of ~10 records fill whole lines).
//   - prep: 8 lanes/output (16 FMA + 3-step shfl_xor), chain 128->16; kc
//     dot-products parallelized across 32 threads.
// R21: register-resident edges, full-chunk specialization.
// R20: 8-lane scalarAgg hops; scatterRes||zd fused; countWrite scales z.
// R19: total linear collapse: logit = A@(A@(A@z+qb)+sb)+c2, z = x.uu+zb0,
//   uu = W1@Wg0@Wg1@Wg2@W2. No GEMM, no 128-dim gather; x read once.
// R18/R17: reservation sort (CAPB=2560) + bucket-local CSR (int2 rp).
// R16: ~150us fixed harness overhead/iter; dispatch boundaries ~free.
// R14/R13: zero per-edge global atomics (returning u64 atomics execute
//   memory-side regardless of scope; 22G/s floor).
// Determinism: deg via fixed-point u32 adds; z/q/s/logit all fp32; bf16 only
//   on edge weights (deterministic per-edge quantization; passed at 0.0039).

#define CAPB  2560      // rec slots per bucket (u64)
#define EDCAP 3584      // edata words per bucket (2560 + 128*7 pad, mult of 8)
#define CHUNK 4096      // edges per scatter block

// ---------- bf16 helper ----------
__device__ __forceinline__ unsigned f2bf(float f) {      // RNE float->bf16 bits
    unsigned u = __float_as_uint(f);
    u += 0x7fffu + ((u >> 16) & 1u);
    return u >> 16;
}

// ---------- prep: uu = W1@Wg0@Wg1@Wg2@W2 chain + scalars + resCur init ----------
// 8 lanes/output: 16 FMAs + 3-step shfl_xor (serial chain 128 -> 16).
// kc = [zb0, qb, sb, c2] = [b1.u0, bg0.wv, bg1.wc2, bg2.W2 + b2]
__global__ __launch_bounds__(1024) void prep_kernel(const float* __restrict__ W1,
                                                    const float* __restrict__ b1,
                                                    const float* __restrict__ Wg,
                                                    const float* __restrict__ bg,
                                                    const float* __restrict__ W2,
                                                    const float* __restrict__ b2,
                                                    float* __restrict__ uu,
                                                    float* __restrict__ kc,
                                                    unsigned* __restrict__ resCur, int NB) {
    __shared__ float wc2[128], wv[128], u0[128];
    int t = threadIdx.x;
    if (t < NB) resCur[t] = (unsigned)t * CAPB;          // bucket reservation cursors
    int o = t >> 3, l = t & 7, j0 = l * 16;              // 128 outputs x 8 lanes

    {   // stage 1: wc2 = Wg2 @ W2
        const float* Wr = Wg + 2 * 16384 + o * 128 + j0;
        float a = 0.f;
#pragma unroll
        for (int j = 0; j < 16; ++j) a += Wr[j] * W2[j0 + j];
        a += __shfl_xor(a, 1); a += __shfl_xor(a, 2); a += __shfl_xor(a, 4);
        if (l == 0) wc2[o] = a;
    }
    __syncthreads();
    {   // stage 2: wv = Wg1 @ wc2
        const float* Wr = Wg + 16384 + o * 128 + j0;
        float a = 0.f;
#pragma unroll
        for (int j = 0; j < 16; ++j) a += Wr[j] * wc2[j0 + j];
        a += __shfl_xor(a, 1); a += __shfl_xor(a, 2); a += __shfl_xor(a, 4);
        if (l == 0) wv[o] = a;
    }
    __syncthreads();
    {   // stage 3: u0 = Wg0 @ wv
        const float* Wr = Wg + o * 128 + j0;
        float a = 0.f;
#pragma unroll
        for (int j = 0; j < 16; ++j) a += Wr[j] * wv[j0 + j];
        a += __shfl_xor(a, 1); a += __shfl_xor(a, 2); a += __shfl_xor(a, 4);
        if (l == 0) u0[o] = a;
    }
    __syncthreads();
    {   // stage 4: uu = W1 @ u0  (global output)
        const float* Wr = W1 + o * 128 + j0;
        float a = 0.f;
#pragma unroll
        for (int j = 0; j < 16; ++j) a += Wr[j] * u0[j0 + j];
        a += __shfl_xor(a, 1); a += __shfl_xor(a, 2); a += __shfl_xor(a, 4);
        if (l == 0) uu[o] = a;
    }
    if (t < 32) {       // kc[g] = va[g] . vb[g]  (+ b2 for g==3)
        int g = t >> 3, l2 = t & 7, k0 = l2 * 16;
        const float* va = (g == 0) ? b1 : (g == 1) ? bg : (g == 2) ? bg + 128 : bg + 256;
        const float* vb = (g == 0) ? u0 : (g == 1) ? wv : (g == 2) ? wc2 : W2;
        float a = 0.f;
#pragma unroll
        for (int j = 0; j < 16; ++j) a += va[k0 + j] * vb[k0 + j];
        a += __shfl_xor(a, 1); a += __shfl_xor(a, 2); a += __shfl_xor(a, 4);
        if (l2 == 0) kc[g] = a + ((g == 3) ? b2[0] : 0.f);
    }
}

// ---------- fused2: scatterRes (blocks [0,NC)) || zd unscaled (blocks [NC,..)) ----------
// scatterRes fast path (full 4096-edge chunk): LDS-staged counting sort ->
//   streaming coalesced rec writes (no partial-line amplification).
// zd: 32 lanes/row; z_i = x_i . uu + zb0 (UNSCALED; countWrite applies dinv).
__global__ __launch_bounds__(1024) void fused2_kernel(const int* __restrict__ row,
                                                      const int* __restrict__ col,
                                                      const float* __restrict__ ew,
                                                      unsigned* __restrict__ resCur,
                                                      unsigned long long* __restrict__ rec,
                                                      const float* __restrict__ x,
                                                      const float* __restrict__ uu,
                                                      const float* __restrict__ kc,
                                                      float* __restrict__ zdv,
                                                      int E, int NB, int NC, int n) {
    __shared__ unsigned long long srec[CHUNK];   // 32KB staged records
    __shared__ unsigned sga[CHUNK];              // 16KB final global index
    __shared__ unsigned cnt[1024];               // histogram -> cursor
    __shared__ unsigned loc[1024];               // inclusive prefix
    __shared__ unsigned gadj[1024];              // gbase - exclusive prefix
    int b = blockIdx.x, t = threadIdx.x;
    if (b < NC) {
        cnt[t] = 0;
        __syncthreads();
        int base = b * CHUNK;
        if (base + CHUNK <= E) {
            // ---- fast path: full chunk, LDS-staged sort ----
            int e0 = base + t * 4;
            int4   c4 = *(const int4*)(col + e0);
            int4   r4 = *(const int4*)(row + e0);
            float4 w4 = *(const float4*)(ew + e0);
            int   c[4] = {c4.x, c4.y, c4.z, c4.w};
            int   r[4] = {r4.x, r4.y, r4.z, r4.w};
            float w[4] = {w4.x, w4.y, w4.z, w4.w};
#pragma unroll
            for (int i = 0; i < 4; ++i)
                atomicAdd(&cnt[(unsigned)c[i] >> 7], 1u);
            __syncthreads();
            unsigned ct = cnt[t];
            // issue global reservation EARLY -- latency hides under the scan
            unsigned gb = ct ? atomicAdd(&resCur[t], ct) : 0u;
            loc[t] = ct;
            __syncthreads();
#pragma unroll
            for (int off = 1; off < 1024; off <<= 1) {   // inclusive scan
                unsigned u = (t >= off) ? loc[t - off] : 0u;
                __syncthreads();
                loc[t] += u;
                __syncthreads();
            }
            unsigned ex = loc[t] - ct;                   // exclusive prefix
            cnt[t]  = ex;                                // block-local cursor
            gadj[t] = gb - ex;                           // slot -> global offset
            __syncthreads();
#pragma unroll
            for (int i = 0; i < 4; ++i) {
                unsigned cc = (unsigned)c[i];
                unsigned bk = cc >> 7;
                unsigned rank = atomicAdd(&cnt[bk], 1u); // LDS cursor
                srec[rank] = ((unsigned long long)(((unsigned)r[i] << 7) | (cc & 127u)) << 32)
                           | (unsigned long long)__float_as_uint(w[i]);
                sga[rank] = gadj[bk] + rank;
            }
            __syncthreads();
#pragma unroll
            for (int k = 0; k < 4; ++k) {                // streaming copy out
                int j = k * 1024 + t;
                rec[sga[j]] = srec[j];
            }
        } else {
            // ---- tail chunk: guarded direct-to-global path ----
            for (int i = 0; i < 4; ++i) {
                int e = base + i * 1024 + t;
                if (e < E) atomicAdd(&cnt[(unsigned)col[e] >> 7], 1u);
            }
            __syncthreads();
            if (t < NB) {
                unsigned cc = cnt[t];
                cnt[t] = cc ? atomicAdd(&resCur[t], cc) : 0u;
            }
            __syncthreads();
            for (int i = 0; i < 4; ++i) {
                int e = base + i * 1024 + t;
                if (e < E) {
                    unsigned cc = (unsigned)col[e];
                    unsigned pos = atomicAdd(&cnt[cc >> 7], 1u);
                    rec[pos] = ((unsigned long long)(((unsigned)row[e] << 7) | (cc & 127u)) << 32)
                             | (unsigned long long)__float_as_uint(ew[e]);
                }
            }
        }
    } else {
        int r = (b - NC) * 32 + (t >> 5);
        int fl = t & 31;                    // 32 lanes x float4 = 128 floats
        if (r < n) {
            float4 xv = ((const float4*)(x + (size_t)r * 128))[fl];
            float4 uv = ((const float4*)uu)[fl];
            float d = xv.x * uv.x + xv.y * uv.y + xv.z * uv.z + xv.w * uv.w;
#pragma unroll
            for (int off = 16; off > 0; off >>= 1) d += __shfl_xor(d, off);
            if (fl == 0) zdv[r] = d + kc[0];            // unscaled z
        }
    }
}

// ---------- countWrite: counts + deg + rp + edata (src, bf16 w) + z scaling ----------
// Bucket-local edata layout (bucket b owns words [b*EDCAP,(b+1)*EDCAP)); rp=(start,end).
__global__ __launch_bounds__(256) void countWrite_kernel(const unsigned long long* __restrict__ rec,
                                                         const unsigned* __restrict__ resCur,
                                                         float* __restrict__ dinv,
                                                         int2* __restrict__ rp,
                                                         unsigned* __restrict__ edata,
                                                         float* __restrict__ zdv,
                                                         int n, int NB) {
    __shared__ unsigned lcnt[128];
    __shared__ unsigned ldeg[128];
    __shared__ unsigned lpre[128];
    __shared__ unsigned curp[128];
    int b = blockIdx.x, t = threadIdx.x;
    unsigned rbase = (unsigned)b * CAPB;
    unsigned tb = min(resCur[b] - rbase, (unsigned)CAPB);   // edges in this bucket
    if (t < 128) { lcnt[t] = 0; ldeg[t] = 0; }
    __syncthreads();
    // 2 edges/thread/iter (16B loads)
    for (unsigned i = t * 2; i < tb; i += 512) {
        unsigned long long r0 = rec[rbase + i];
        unsigned cl0 = (unsigned)(r0 >> 32) & 127u;
        float wv0 = __uint_as_float((unsigned)r0);
        atomicAdd(&lcnt[cl0], 1u);
        atomicAdd(&ldeg[cl0], (unsigned)(wv0 * 16777216.0f));   // same truncation as R12
        if (i + 1 < tb) {
            unsigned long long r1 = rec[rbase + i + 1];
            unsigned cl1 = (unsigned)(r1 >> 32) & 127u;
            float wv1 = __uint_as_float((unsigned)r1);
            atomicAdd(&lcnt[cl1], 1u);
            atomicAdd(&ldeg[cl1], (unsigned)(wv1 * 16777216.0f));
        }
    }
    __syncthreads();
    int node = b * 128 + t;
    unsigned c = 0, pv = 0;
    if (t < 128) {
        if (node < n) { c = lcnt[t]; pv = (c + 7) & ~7u; }
        lpre[t] = pv;
    }
    __syncthreads();
    for (int off = 1; off < 128; off <<= 1) {               // inclusive scan over 128
        unsigned u = (t < 128 && t >= off) ? lpre[t - off] : 0;
        __syncthreads();
        if (t < 128) lpre[t] += u;
        __syncthreads();
    }
    if (t < 128 && node < n) {
        unsigned st = (unsigned)b * EDCAP + lpre[t] - pv;   // bucket-local exclusive
        float di = rsqrtf(1.0f + (float)ldeg[t] * (1.0f / 16777216.0f));
        dinv[node] = di;
        zdv[node] *= di;                                    // scale z (was unscaled)
        rp[node] = make_int2((int)st, (int)(st + pv));
        curp[t] = st;
        for (unsigned z = c; z < pv; ++z) edata[st + z] = 0;   // zero pad slots
    }
    __syncthreads();
    for (unsigned i = t; i < tb; i += 256) {
        unsigned long long r = rec[rbase + i];
        unsigned key = (unsigned)(r >> 32);
        unsigned cl = key & 127u, src = key >> 7;
        float w = __uint_as_float((unsigned)r);
        unsigned pos = atomicAdd(&curp[cl], 1u);            // LDS cursor
        edata[pos] = (src << 15) | (f2bf(w) & 0x7fffu);     // raw weight only
    }
}

// ---------- scalar aggregation, 8 lanes/node: v_out = di*(acc + vals[i]) + K ----------
// vals pre-scaled by dinv; segments padded to mult of 8 -> full 8-lane groups,
// no divergence (pads have w=0). FINAL=0: write v_out*di. FINAL=1: sigmoid.
template<int FINAL>
__global__ __launch_bounds__(256) void scalarAgg_kernel(const float* __restrict__ vals,
                                                        const int2* __restrict__ rp,
                                                        const unsigned* __restrict__ edata,
                                                        const float* __restrict__ dinv,
                                                        const float* __restrict__ kc,
                                                        float* __restrict__ out, int n) {
    int gid  = blockIdx.x * 256 + threadIdx.x;
    int wid  = gid >> 3;
    int l8   = gid & 7;
    if (wid >= n) return;
    int2 seg = rp[wid];
    float acc = 0.f;
    for (int idx = seg.x + l8; idx < seg.y; idx += 8) {
        unsigned ed = edata[idx];             // pads: w=0, src=0 -> harmless
        float w = __uint_as_float((ed & 0x7fffu) << 16);
        acc += w * vals[ed >> 15];
    }
#pragma unroll
    for (int off = 4; off > 0; off >>= 1) acc += __shfl_xor(acc, off);
    if (l8 == 0) {
        float di = dinv[wid];
        float d = di * (acc + vals[wid]) + kc[0];
        out[wid] = FINAL ? 1.0f / (1.0f + expf(-d)) : d * di;
    }
}

static inline char* align16(char* p) { return (char*)(((uintptr_t)p + 15) & ~(uintptr_t)15); }

extern "C" void kernel_launch(void* const* d_in, const int* in_sizes, int n_in,
                              void* d_out, int out_size, void* d_ws, size_t ws_size,
                              hipStream_t stream) {
    const float* x  = (const float*)d_in[0];
    const int*   ei = (const int*)d_in[1];   // [2, E] int32
    const float* ea = (const float*)d_in[2]; // [E]
    const float* W1 = (const float*)d_in[3];
    const float* b1 = (const float*)d_in[4];
    const float* Wg = (const float*)d_in[5]; // [3,128,128]
    const float* bg = (const float*)d_in[6]; // [3,128]
    const float* W2 = (const float*)d_in[7]; // [128]
    const float* b2 = (const float*)d_in[8]; // [1]

    const int N = in_sizes[0] / 128;
    const int E = in_sizes[2];
    const int* row = ei;
    const int* col = ei + E;

    const int NB = (N + 127) >> 7;           // buckets of 128 nodes (782)
    const int NC = (E + CHUNK - 1) / CHUNK;  // 4096-edge chunks (391)
    const int NZ = (N + 31) >> 5;            // zd blocks (32 rows each @1024thr)

    // workspace layout
    char* p = (char*)d_ws;
    unsigned long long* rec = (unsigned long long*)p; p += (size_t)NB * CAPB * 8; // 16MB
    float* uu  = (float*)p;  p += 128 * 4;
    float* kc  = (float*)p;  p += 16;
    float* zdv = (float*)p;  p += (size_t)N * 4;
    float* qdv = (float*)p;  p += (size_t)N * 4;
    float* sdv = (float*)p;  p += (size_t)N * 4;
    p = align16(p);
    unsigned* resCur = (unsigned*)p; p += (size_t)NB * 4; p = align16(p);
    float* dinv = (float*)p; p += (size_t)N * 4;
    int2* rp    = (int2*)p;  p += (size_t)N * 8; p = align16(p);
    unsigned* edata = (unsigned*)p;            // NB*EDCAP words (~11.2MB)

    dim3 b256(256);
    int agg_blocks = (int)(((size_t)N * 8 + 255) / 256);   // 8 lanes / node

    // D1: weight-chain collapse (uu, kc) + reservation cursors
    prep_kernel<<<1, dim3(1024), 0, stream>>>(W1, b1, Wg, bg, W2, b2, uu, kc, resCur, NB);
    // D2: scatterRes || zd (independent; zd writes unscaled z)
    fused2_kernel<<<NC + NZ, dim3(1024), 0, stream>>>(row, col, ea, resCur, rec,
                                                      x, uu, kc, zdv, E, NB, NC, N);
    // D3: per-bucket counts + deg/dinv + rp + edata(src, bf16 w) + z scaling
    countWrite_kernel<<<NB, b256, 0, stream>>>(rec, resCur, dinv, rp, edata, zdv, N, NB);
    // D4-D6: three scalar hops  q -> s -> logit/sigmoid (8 lanes/node)
    scalarAgg_kernel<0><<<agg_blocks, b256, 0, stream>>>(zdv, rp, edata, dinv, kc + 1, qdv, N);
    scalarAgg_kernel<0><<<agg_blocks, b256, 0, stream>>>(qdv, rp, edata, dinv, kc + 2, sdv, N);
    scalarAgg_kernel<1><<<agg_blocks, b256, 0, stream>>>(sdv, rp, edata, dinv, kc + 3,
                                                         (float*)d_out, N);
}